// Round 9
// baseline (146.352 us; speedup 1.0000x reference)
//
#include <hip/hip_runtime.h>
#include <math.h>

namespace {
constexpr int kN    = 8192;
constexpr int kC    = 256;
constexpr int kTAB  = 3025;
constexpr int kRowsTotal = 2 * kN;  // B*N = 16384
constexpr float kScale = 0.17677669529663687f;  // 32^-0.5
}

typedef __attribute__((ext_vector_type(8))) short bf16x8;
typedef __attribute__((ext_vector_type(4))) float f32x4;

__device__ __forceinline__ unsigned short f2bf(float f) {
  unsigned int u = __float_as_uint(f);
  u += 0x7fffu + ((u >> 16) & 1u);   // round-to-nearest-even
  return (unsigned short)(u >> 16);
}
__device__ __forceinline__ float bflo(unsigned int u) {
  return __uint_as_float(u << 16);
}
__device__ __forceinline__ float bfhi(unsigned int u) {
  return __uint_as_float(u & 0xffff0000u);
}

#define GLOAD16(g, l)                                                   \
  __builtin_amdgcn_global_load_lds(                                     \
      (const __attribute__((address_space(1))) void*)(g),               \
      (__attribute__((address_space(3))) void*)(l), 16, 0, 0)

// ---------------- LayerNorm -> bf16 (wave per row, no barriers) --------------
__global__ __launch_bounds__(256) void ln_bf16_kernel(
    const float* __restrict__ x, const float* __restrict__ w,
    const float* __restrict__ b, unsigned short* __restrict__ o) {
  int t = threadIdx.x;
  int row = blockIdx.x * 4 + (t >> 6);
  int l = t & 63;
  float4 v = *(const float4*)(x + (size_t)row * kC + l * 4);
  float s  = v.x + v.y + v.z + v.w;
  float s2 = v.x * v.x + v.y * v.y + v.z * v.z + v.w * v.w;
#pragma unroll
  for (int d = 1; d < 64; d <<= 1) {
    s  += __shfl_xor(s, d, 64);
    s2 += __shfl_xor(s2, d, 64);
  }
  float mu = s * (1.0f / kC);
  float rstd = rsqrtf(s2 * (1.0f / kC) - mu * mu + 1e-5f);
  float4 wv = *(const float4*)(w + l * 4);
  float4 bv = *(const float4*)(b + l * 4);
  unsigned short o0 = f2bf((v.x - mu) * rstd * wv.x + bv.x);
  unsigned short o1 = f2bf((v.y - mu) * rstd * wv.y + bv.y);
  unsigned short o2 = f2bf((v.z - mu) * rstd * wv.z + bv.z);
  unsigned short o3 = f2bf((v.w - mu) * rstd * wv.w + bv.w);
  uint2 ov;
  ov.x = ((unsigned int)o1 << 16) | o0;
  ov.y = ((unsigned int)o3 << 16) | o2;
  *(uint2*)(o + (size_t)row * kC + l * 4) = ov;
}

// ---------------- PE table ----------------
__global__ __launch_bounds__(256) void pe_kernel(const float* __restrict__ tab,
                                                 const float* __restrict__ pw,
                                                 const float* __restrict__ pb,
                                                 float* __restrict__ outp) {
  int i = blockIdx.x * 256 + threadIdx.x;
  if (i >= kTAB * 8) return;
  int r = i >> 3, h = i & 7;
  float acc = pb[h];
#pragma unroll
  for (int f = 0; f < 5; ++f) acc += tab[r * 5 + f] * pw[h * 5 + f];
  outp[i] = acc;
}

// ---------------- cast weights to bf16 (+ concat qkv bias) ----------------
__global__ __launch_bounds__(256) void cast_weights_kernel(
    const float* __restrict__ qw, const float* __restrict__ kvw,
    const float* __restrict__ pjw, const float* __restrict__ f1w,
    const float* __restrict__ f2w, const float* __restrict__ qb,
    const float* __restrict__ kvb, unsigned short* __restrict__ wqkv,
    unsigned short* __restrict__ wproj, unsigned short* __restrict__ wfc1,
    unsigned short* __restrict__ wfc2, float* __restrict__ bqkv) {
  int i = blockIdx.x * 256 + threadIdx.x;
  if (i < 65536)       wqkv[i]            = f2bf(qw[i]);
  else if (i < 196608) wqkv[i]            = f2bf(kvw[i - 65536]);
  else if (i < 262144) wproj[i - 196608]  = f2bf(pjw[i - 196608]);
  else if (i < 393216) wfc1[i - 262144]   = f2bf(f1w[i - 262144]);
  else if (i < 524288) wfc2[i - 393216]   = f2bf(f2w[i - 393216]);
  else if (i < 524544) bqkv[i - 524288]   = qb[i - 524288];
  else if (i < 525056) bqkv[i - 524288]   = kvb[i - 524544];
}

// ---- bf16 MFMA GEMM: BM=64, BN=256, 8 waves (512 thr), BK=64 double-buffer --
template <int EPI, int KDIM>
__global__ __launch_bounds__(512) void gemm64(
    const unsigned short* __restrict__ A, const unsigned short* __restrict__ Wt,
    const float* __restrict__ bias, void* __restrict__ o1,
    unsigned short* __restrict__ o2, unsigned short* __restrict__ o3,
    const float* __restrict__ res, const float* __restrict__ w2,
    const float* __restrict__ b2, unsigned short* __restrict__ yln) {
  __shared__ alignas(16) unsigned short smem[40960];
  unsigned short* As0 = smem;
  unsigned short* Bs0 = smem + 8192;
  int t = threadIdx.x;
  int w = t >> 6, l = t & 63;
  int bm = blockIdx.x * 64, bn = blockIdx.y * 256;

  f32x4 acc[4][2] = {};

  const size_t aoff = (size_t)(bm + w * 8 + (l >> 3)) * KDIM + (l & 7) * 8;
  const size_t boff = (size_t)(bn + w * 32 + (l >> 3)) * KDIM + (l & 7) * 8;
  const int lr = l & 15, lk = l >> 4;

#define STAGE_T(buf, k0)                                                      \
  do {                                                                        \
    GLOAD16(A + aoff + (k0), As0 + (buf)*4096 + w * 512 + l * 8);             \
    GLOAD16(Wt + boff + (k0), Bs0 + (buf)*16384 + w * 2048 + l * 8);          \
    GLOAD16(Wt + boff + (k0) + (size_t)8 * KDIM,                              \
            Bs0 + (buf)*16384 + w * 2048 + 512 + l * 8);                      \
    GLOAD16(Wt + boff + (k0) + (size_t)16 * KDIM,                             \
            Bs0 + (buf)*16384 + w * 2048 + 1024 + l * 8);                     \
    GLOAD16(Wt + boff + (k0) + (size_t)24 * KDIM,                             \
            Bs0 + (buf)*16384 + w * 2048 + 1536 + l * 8);                     \
  } while (0)

  auto compute = [&](int buf) {
#pragma unroll
    for (int kk = 0; kk < 2; ++kk) {
      bf16x8 af[4], bfr[2];
#pragma unroll
      for (int mi = 0; mi < 4; ++mi)
        af[mi] = *(const bf16x8*)(As0 + buf * 4096 + (mi * 16 + lr) * 64 +
                                  kk * 32 + lk * 8);
#pragma unroll
      for (int ni = 0; ni < 2; ++ni)
        bfr[ni] = *(const bf16x8*)(Bs0 + buf * 16384 +
                                   (w * 32 + ni * 16 + lr) * 64 + kk * 32 +
                                   lk * 8);
#pragma unroll
      for (int mi = 0; mi < 4; ++mi)
#pragma unroll
        for (int ni = 0; ni < 2; ++ni)
          acc[mi][ni] = __builtin_amdgcn_mfma_f32_16x16x32_bf16(
              af[mi], bfr[ni], acc[mi][ni], 0, 0, 0);
    }
  };

  STAGE_T(0, 0);
  __syncthreads();
  int cur = 0;
#pragma unroll
  for (int k0 = 64; k0 < KDIM; k0 += 64) {
    STAGE_T(cur ^ 1, k0);
    compute(cur);
    __syncthreads();
    cur ^= 1;
  }
  compute(cur);

  if constexpr (EPI == 1) {
    __syncthreads();
    float* xs = (float*)smem;
#pragma unroll
    for (int mi = 0; mi < 4; ++mi) {
#pragma unroll
      for (int ni = 0; ni < 2; ++ni) {
        int c = w * 32 + ni * 16 + lr;
        float bv = bias[c];
#pragma unroll
        for (int j = 0; j < 4; ++j) {
          int rl = mi * 16 + lk * 4 + j;
          float x = acc[mi][ni][j] + bv + res[(size_t)(bm + rl) * 256 + c];
          xs[rl * 260 + c] = x;
          ((float*)o1)[(size_t)(bm + rl) * 256 + c] = x;
        }
      }
    }
    __syncthreads();
    int r = t >> 3, sub = t & 7;
    float4 xv[8];
    float sx = 0.f, sxx = 0.f;
#pragma unroll
    for (int i = 0; i < 8; ++i) {
      xv[i] = *(const float4*)&xs[r * 260 + sub * 4 + i * 32];
      sx  += xv[i].x + xv[i].y + xv[i].z + xv[i].w;
      sxx += xv[i].x * xv[i].x + xv[i].y * xv[i].y + xv[i].z * xv[i].z +
             xv[i].w * xv[i].w;
    }
#pragma unroll
    for (int d = 1; d < 8; d <<= 1) {
      sx  += __shfl_xor(sx, d, 64);
      sxx += __shfl_xor(sxx, d, 64);
    }
    float mu = sx * (1.0f / 256.0f);
    float rstd = rsqrtf(sxx * (1.0f / 256.0f) - mu * mu + 1e-5f);
#pragma unroll
    for (int i = 0; i < 8; ++i) {
      int c = sub * 4 + i * 32;
      float4 wv = *(const float4*)(w2 + c);
      float4 bv = *(const float4*)(b2 + c);
      unsigned short y0 = f2bf((xv[i].x - mu) * rstd * wv.x + bv.x);
      unsigned short y1 = f2bf((xv[i].y - mu) * rstd * wv.y + bv.y);
      unsigned short y2 = f2bf((xv[i].z - mu) * rstd * wv.z + bv.z);
      unsigned short y3 = f2bf((xv[i].w - mu) * rstd * wv.w + bv.w);
      uint2 ov;
      ov.x = ((unsigned int)y1 << 16) | y0;
      ov.y = ((unsigned int)y3 << 16) | y2;
      *(uint2*)(yln + (size_t)(bm + r) * 256 + c) = ov;
    }
  } else {
#pragma unroll
    for (int mi = 0; mi < 4; ++mi) {
#pragma unroll
      for (int ni = 0; ni < 2; ++ni) {
        int col = bn + w * 32 + ni * 16 + lr;
        float bv = bias[col];
#pragma unroll
        for (int j = 0; j < 4; ++j) {
          int rg = bm + mi * 16 + lk * 4 + j;
          float x = acc[mi][ni][j] + bv;
          if constexpr (EPI == 0) {
            if (col < 256) {
              ((unsigned short*)o1)[(size_t)rg * 256 + col] = f2bf(x * kScale);
            } else {
              int c = col - 256;
              int h = c >> 6, sbit = (c >> 5) & 1, ch = c & 31;
              unsigned short* dst = sbit ? o3 : o2;
              dst[(size_t)rg * 256 + h * 32 + ch] = f2bf(x);
            }
          } else if constexpr (EPI == 2) {
            float g = 0.5f * x * (1.0f + erff(x * 0.70710678118654752f));
            ((unsigned short*)o1)[(size_t)rg * 512 + col] = f2bf(g);
          } else {
            ((float*)o1)[(size_t)rg * 256 + col] =
                res[(size_t)rg * 256 + col] + x;
          }
        }
      }
    }
  }
#undef STAGE_T
}

// -------- Attention: (batch x head-pair) -> XCD partition, wave per unit -----
// bid&7 -> partition (b = p>>2, hg = p&3). Each XCD touches only its 2 MB
// K/V head-pair slice (1 line per row). Wave = one (token, head-pair):
// QK: lane (h=l>>5, m=l&31) computes logit[h][m] (128B/member across wave).
// softmax: 5-step shfl_xor in each 32-lane half.
// PV: transposed via LDS; lane (h, s=(l>>4)&1, c16=l&15) -> 2 channels,
// 16 members; coalesced 64B per 16-lane group; s-halves combined by shfl.
__global__ __launch_bounds__(256) void attn_kernel(
    const unsigned short* __restrict__ q, const unsigned short* __restrict__ k,
    const unsigned short* __restrict__ v, const int* __restrict__ member_idx,
    const int* __restrict__ pe_idx, const float* __restrict__ cmask,
    const float* __restrict__ pe_full, const float* __restrict__ blank_k,
    const float* __restrict__ blank_v, unsigned short* __restrict__ outp) {
  int t = threadIdx.x;
  int w = t >> 6, l = t & 63;
  int bid = blockIdx.x;
  int part = bid & 7;
  int bb = part >> 2, hg = part & 3;
  int row = bb * kN + (bid >> 3) * 4 + w;
  const size_t kvbase = (size_t)bb * kN;
  const int hloc = l >> 5, m = l & 31;
  const int head = hg * 2 + hloc;

  __shared__ float aw[4][2][34];
  __shared__ int   idxs[4][32];

  // ---- per-lane member metadata (coalesced; 2x broadcast merged) ----
  int   idxv = member_idx[(size_t)row * 32 + m];
  float mk   = (1.0f - cmask[(size_t)row * 32 + m]) * -100.0f;
  float pe   = pe_full[(size_t)pe_idx[(size_t)row * 32 + m] * 8 + head];
  if (l < 32) idxs[w][l] = idxv;

  // ---- q slice for this head: 32 f32 (broadcast within 32-lane half) ----
  float qf[32];
#pragma unroll
  for (int i = 0; i < 8; ++i) {
    uint2 qu = *(const uint2*)(q + (size_t)row * 256 + head * 32 + i * 4);
    qf[4 * i + 0] = bflo(qu.x);
    qf[4 * i + 1] = bfhi(qu.x);
    qf[4 * i + 2] = bflo(qu.y);
    qf[4 * i + 3] = bfhi(qu.y);
  }

  // ---- QK logit: lane reads 64B K slice of its member/head ----
  const uint4* kr = (const uint4*)(k + (kvbase + idxv) * 256 + head * 32);
  float lg = 0.f;
#pragma unroll
  for (int j = 0; j < 4; ++j) {
    uint4 u = kr[j];
    lg = fmaf(qf[8 * j + 0], bflo(u.x), lg);
    lg = fmaf(qf[8 * j + 1], bfhi(u.x), lg);
    lg = fmaf(qf[8 * j + 2], bflo(u.y), lg);
    lg = fmaf(qf[8 * j + 3], bfhi(u.y), lg);
    lg = fmaf(qf[8 * j + 4], bflo(u.z), lg);
    lg = fmaf(qf[8 * j + 5], bfhi(u.z), lg);
    lg = fmaf(qf[8 * j + 6], bflo(u.w), lg);
    lg = fmaf(qf[8 * j + 7], bfhi(u.w), lg);
  }
  lg += mk + pe;

  // ---- blank logit (redundant, identical within half) ----
  float bl = 0.f;
#pragma unroll
  for (int i = 0; i < 8; ++i) {
    float4 bk = *(const float4*)(blank_k + head * 32 + i * 4);
    bl += qf[4 * i] * bk.x + qf[4 * i + 1] * bk.y + qf[4 * i + 2] * bk.z +
          qf[4 * i + 3] * bk.w;
  }
  bl = fminf(fmaxf(bl, -5.0f), 5.0f);

  // ---- softmax over 33 within the 32-lane half ----
  float mx = lg;
#pragma unroll
  for (int d = 1; d < 32; d <<= 1) mx = fmaxf(mx, __shfl_xor(mx, d, 64));
  mx = fmaxf(mx, bl);
  float e = __expf(lg - mx);
  float s = e;
#pragma unroll
  for (int d = 1; d < 32; d <<= 1) s += __shfl_xor(s, d, 64);
  float eb = __expf(bl - mx);
  s += eb;
  float inv = __builtin_amdgcn_rcpf(s);
  aw[w][hloc][m] = e * inv;
  if (m == 0) aw[w][hloc][32] = eb * inv;
  __syncthreads();

  // ---- PV: lane (h, s, c16) -> channels c16*2..+1, members s*16..+15 ----
  const int sgrp = (l >> 4) & 1, c16 = l & 15;
  const int hp = l >> 5;  // same as hloc
  const unsigned short* vb = v + (hg * 2 + hp) * 32 + c16 * 2;
  float ax = 0.f, ay = 0.f;
#pragma unroll
  for (int i = 0; i < 16; ++i) {
    int mm = sgrp * 16 + i;
    float a = aw[w][hp][mm];
    unsigned int u = *(const unsigned int*)(vb + (kvbase + idxs[w][mm]) * 256);
    ax = fmaf(a, bflo(u), ax);
    ay = fmaf(a, bfhi(u), ay);
  }
  ax += __shfl_xor(ax, 16, 64);
  ay += __shfl_xor(ay, 16, 64);
  if (sgrp == 0) {
    float ab = aw[w][hp][32];
    int c = (hg * 2 + hp) * 32 + c16 * 2;
    ax = fmaf(ab, blank_v[c], ax);
    ay = fmaf(ab, blank_v[c + 1], ay);
    unsigned int o = ((unsigned int)f2bf(ay) << 16) | f2bf(ax);
    *(unsigned int*)(outp + (size_t)row * 256 + c) = o;
  }
}

extern "C" void kernel_launch(void* const* d_in, const int* in_sizes, int n_in,
                              void* d_out, int out_size, void* d_ws, size_t ws_size,
                              hipStream_t stream) {
  const float* feat       = (const float*)d_in[0];
  const int*   member_idx = (const int*)d_in[1];
  const float* cmask      = (const float*)d_in[2];
  const int*   pe_idx     = (const int*)d_in[3];
  const float* pre_table  = (const float*)d_in[5];
  const float* n1w        = (const float*)d_in[6];
  const float* n1b        = (const float*)d_in[7];
  const float* q_w        = (const float*)d_in[8];
  const float* q_b        = (const float*)d_in[9];
  const float* kv_w       = (const float*)d_in[10];
  const float* kv_b       = (const float*)d_in[11];
  const float* blank_k    = (const float*)d_in[12];
  const float* blank_v    = (const float*)d_in[13];
  const float* pe_w       = (const float*)d_in[14];
  const float* pe_b       = (const float*)d_in[15];
  const float* proj_w     = (const float*)d_in[16];
  const float* proj_b     = (const float*)d_in[17];
  const float* n2w        = (const float*)d_in[18];
  const float* n2b        = (const float*)d_in[19];
  const float* fc1_w      = (const float*)d_in[20];
  const float* fc1_b      = (const float*)d_in[21];
  const float* fc2_w      = (const float*)d_in[22];
  const float* fc2_b      = (const float*)d_in[23];

  float* out = (float*)d_out;
  unsigned char* ws = (unsigned char*)d_ws;

  unsigned short* xln   = (unsigned short*)(ws + 0);           // 8 MB, later attn_out
  unsigned short* q_buf = (unsigned short*)(ws + 8388608);     // 8 MB, later yln
  unsigned short* k_buf = (unsigned short*)(ws + 16777216);    // 8 MB \ later h1 (16MB)
  unsigned short* v_buf = (unsigned short*)(ws + 25165824);    // 8 MB /
  unsigned short* wqkv  = (unsigned short*)(ws + 33554432);    // 384 KB
  unsigned short* wproj = (unsigned short*)(ws + 33947648);    // 128 KB
  unsigned short* wfc1  = (unsigned short*)(ws + 34078720);    // 256 KB
  unsigned short* wfc2  = (unsigned short*)(ws + 34340864);    // 256 KB
  float*          bqkv  = (float*)(ws + 34603008);             // 3 KB
  float*          pe_buf= (float*)(ws + 34606080);             // ~97 KB
  unsigned short* attn_out = xln;
  unsigned short* yln   = q_buf;
  unsigned short* h1    = k_buf;   // 16 MB spanning k_buf+v_buf

  cast_weights_kernel<<<2052, 256, 0, stream>>>(
      q_w, kv_w, proj_w, fc1_w, fc2_w, q_b, kv_b, wqkv, wproj, wfc1, wfc2, bqkv);
  pe_kernel<<<(kTAB * 8 + 255) / 256, 256, 0, stream>>>(pre_table, pe_w, pe_b, pe_buf);
  ln_bf16_kernel<<<kRowsTotal / 4, 256, 0, stream>>>(feat, n1w, n1b, xln);

  gemm64<0, 256><<<dim3(kRowsTotal / 64, 3), 512, 0, stream>>>(
      xln, wqkv, bqkv, q_buf, k_buf, v_buf, nullptr, nullptr, nullptr, nullptr);

  // 16384 blocks: 8 partitions (batch x head-pair) x 2048 token-groups
  attn_kernel<<<kRowsTotal, 256, 0, stream>>>(
      q_buf, k_buf, v_buf, member_idx, pe_idx, cmask, pe_buf, blank_k, blank_v,
      attn_out);

  gemm64<1, 256><<<dim3(kRowsTotal / 64, 1), 512, 0, stream>>>(
      attn_out, wproj, proj_b, out, nullptr, nullptr, feat, n2w, n2b, yln);

  gemm64<2, 256><<<dim3(kRowsTotal / 64, 2), 512, 0, stream>>>(
      yln, wfc1, fc1_b, h1, nullptr, nullptr, nullptr, nullptr, nullptr, nullptr);

  gemm64<3, 512><<<dim3(kRowsTotal / 64, 1), 512, 0, stream>>>(
      h1, wfc2, fc2_b, out, nullptr, nullptr, out, nullptr, nullptr, nullptr);
}

// Round 11
// 131.104 us; speedup vs baseline: 1.1163x; 1.1163x over previous
//
#include <hip/hip_runtime.h>
#include <math.h>

namespace {
constexpr int kN    = 8192;
constexpr int kC    = 256;
constexpr int kTAB  = 3025;
constexpr int kRowsTotal = 2 * kN;  // B*N = 16384
constexpr float kScale = 0.17677669529663687f;  // 32^-0.5
}

typedef __attribute__((ext_vector_type(8))) short bf16x8;
typedef __attribute__((ext_vector_type(4))) float f32x4;

__device__ __forceinline__ unsigned short f2bf(float f) {
  unsigned int u = __float_as_uint(f);
  u += 0x7fffu + ((u >> 16) & 1u);   // round-to-nearest-even
  return (unsigned short)(u >> 16);
}
__device__ __forceinline__ float bflo(unsigned int u) {
  return __uint_as_float(u << 16);
}
__device__ __forceinline__ float bfhi(unsigned int u) {
  return __uint_as_float(u & 0xffff0000u);
}

#define GLOAD16(g, l)                                                   \
  __builtin_amdgcn_global_load_lds(                                     \
      (const __attribute__((address_space(1))) void*)(g),               \
      (__attribute__((address_space(3))) void*)(l), 16, 0, 0)

// ---------------- LayerNorm -> bf16 (wave per row, no barriers) --------------
__global__ __launch_bounds__(256) void ln_bf16_kernel(
    const float* __restrict__ x, const float* __restrict__ w,
    const float* __restrict__ b, unsigned short* __restrict__ o) {
  int t = threadIdx.x;
  int row = blockIdx.x * 4 + (t >> 6);
  int l = t & 63;
  float4 v = *(const float4*)(x + (size_t)row * kC + l * 4);
  float s  = v.x + v.y + v.z + v.w;
  float s2 = v.x * v.x + v.y * v.y + v.z * v.z + v.w * v.w;
#pragma unroll
  for (int d = 1; d < 64; d <<= 1) {
    s  += __shfl_xor(s, d, 64);
    s2 += __shfl_xor(s2, d, 64);
  }
  float mu = s * (1.0f / kC);
  float rstd = rsqrtf(s2 * (1.0f / kC) - mu * mu + 1e-5f);
  float4 wv = *(const float4*)(w + l * 4);
  float4 bv = *(const float4*)(b + l * 4);
  unsigned short o0 = f2bf((v.x - mu) * rstd * wv.x + bv.x);
  unsigned short o1 = f2bf((v.y - mu) * rstd * wv.y + bv.y);
  unsigned short o2 = f2bf((v.z - mu) * rstd * wv.z + bv.z);
  unsigned short o3 = f2bf((v.w - mu) * rstd * wv.w + bv.w);
  uint2 ov;
  ov.x = ((unsigned int)o1 << 16) | o0;
  ov.y = ((unsigned int)o3 << 16) | o2;
  *(uint2*)(o + (size_t)row * kC + l * 4) = ov;
}

// ---------------- PE table ----------------
__global__ __launch_bounds__(256) void pe_kernel(const float* __restrict__ tab,
                                                 const float* __restrict__ pw,
                                                 const float* __restrict__ pb,
                                                 float* __restrict__ outp) {
  int i = blockIdx.x * 256 + threadIdx.x;
  if (i >= kTAB * 8) return;
  int r = i >> 3, h = i & 7;
  float acc = pb[h];
#pragma unroll
  for (int f = 0; f < 5; ++f) acc += tab[r * 5 + f] * pw[h * 5 + f];
  outp[i] = acc;
}

// ---------------- cast weights to bf16 (+ concat qkv bias) ----------------
__global__ __launch_bounds__(256) void cast_weights_kernel(
    const float* __restrict__ qw, const float* __restrict__ kvw,
    const float* __restrict__ pjw, const float* __restrict__ f1w,
    const float* __restrict__ f2w, const float* __restrict__ qb,
    const float* __restrict__ kvb, unsigned short* __restrict__ wqkv,
    unsigned short* __restrict__ wproj, unsigned short* __restrict__ wfc1,
    unsigned short* __restrict__ wfc2, float* __restrict__ bqkv) {
  int i = blockIdx.x * 256 + threadIdx.x;
  if (i < 65536)       wqkv[i]            = f2bf(qw[i]);
  else if (i < 196608) wqkv[i]            = f2bf(kvw[i - 65536]);
  else if (i < 262144) wproj[i - 196608]  = f2bf(pjw[i - 196608]);
  else if (i < 393216) wfc1[i - 262144]   = f2bf(f1w[i - 262144]);
  else if (i < 524288) wfc2[i - 393216]   = f2bf(f2w[i - 393216]);
  else if (i < 524544) bqkv[i - 524288]   = qb[i - 524288];
  else if (i < 525056) bqkv[i - 524288]   = kvb[i - 524544];
}

// ---- bf16 MFMA GEMM: BM=64, BN=256, 8 waves (512 thr), BK=64 double-buffer --
template <int EPI, int KDIM>
__global__ __launch_bounds__(512) void gemm64(
    const unsigned short* __restrict__ A, const unsigned short* __restrict__ Wt,
    const float* __restrict__ bias, void* __restrict__ o1,
    unsigned short* __restrict__ o2, unsigned short* __restrict__ o3,
    const float* __restrict__ res, const float* __restrict__ w2,
    const float* __restrict__ b2, unsigned short* __restrict__ yln) {
  __shared__ alignas(16) unsigned short smem[40960];
  unsigned short* As0 = smem;
  unsigned short* Bs0 = smem + 8192;
  int t = threadIdx.x;
  int w = t >> 6, l = t & 63;
  int bm = blockIdx.x * 64, bn = blockIdx.y * 256;

  f32x4 acc[4][2] = {};

  const size_t aoff = (size_t)(bm + w * 8 + (l >> 3)) * KDIM + (l & 7) * 8;
  const size_t boff = (size_t)(bn + w * 32 + (l >> 3)) * KDIM + (l & 7) * 8;
  const int lr = l & 15, lk = l >> 4;

#define STAGE_T(buf, k0)                                                      \
  do {                                                                        \
    GLOAD16(A + aoff + (k0), As0 + (buf)*4096 + w * 512 + l * 8);             \
    GLOAD16(Wt + boff + (k0), Bs0 + (buf)*16384 + w * 2048 + l * 8);          \
    GLOAD16(Wt + boff + (k0) + (size_t)8 * KDIM,                              \
            Bs0 + (buf)*16384 + w * 2048 + 512 + l * 8);                      \
    GLOAD16(Wt + boff + (k0) + (size_t)16 * KDIM,                             \
            Bs0 + (buf)*16384 + w * 2048 + 1024 + l * 8);                     \
    GLOAD16(Wt + boff + (k0) + (size_t)24 * KDIM,                             \
            Bs0 + (buf)*16384 + w * 2048 + 1536 + l * 8);                     \
  } while (0)

  auto compute = [&](int buf) {
#pragma unroll
    for (int kk = 0; kk < 2; ++kk) {
      bf16x8 af[4], bfr[2];
#pragma unroll
      for (int mi = 0; mi < 4; ++mi)
        af[mi] = *(const bf16x8*)(As0 + buf * 4096 + (mi * 16 + lr) * 64 +
                                  kk * 32 + lk * 8);
#pragma unroll
      for (int ni = 0; ni < 2; ++ni)
        bfr[ni] = *(const bf16x8*)(Bs0 + buf * 16384 +
                                   (w * 32 + ni * 16 + lr) * 64 + kk * 32 +
                                   lk * 8);
#pragma unroll
      for (int mi = 0; mi < 4; ++mi)
#pragma unroll
        for (int ni = 0; ni < 2; ++ni)
          acc[mi][ni] = __builtin_amdgcn_mfma_f32_16x16x32_bf16(
              af[mi], bfr[ni], acc[mi][ni], 0, 0, 0);
    }
  };

  STAGE_T(0, 0);
  __syncthreads();
  int cur = 0;
#pragma unroll
  for (int k0 = 64; k0 < KDIM; k0 += 64) {
    STAGE_T(cur ^ 1, k0);
    compute(cur);
    __syncthreads();
    cur ^= 1;
  }
  compute(cur);

  if constexpr (EPI == 1) {
    __syncthreads();
    float* xs = (float*)smem;
#pragma unroll
    for (int mi = 0; mi < 4; ++mi) {
#pragma unroll
      for (int ni = 0; ni < 2; ++ni) {
        int c = w * 32 + ni * 16 + lr;
        float bv = bias[c];
#pragma unroll
        for (int j = 0; j < 4; ++j) {
          int rl = mi * 16 + lk * 4 + j;
          float x = acc[mi][ni][j] + bv + res[(size_t)(bm + rl) * 256 + c];
          xs[rl * 260 + c] = x;
          ((float*)o1)[(size_t)(bm + rl) * 256 + c] = x;
        }
      }
    }
    __syncthreads();
    int r = t >> 3, sub = t & 7;
    float4 xv[8];
    float sx = 0.f, sxx = 0.f;
#pragma unroll
    for (int i = 0; i < 8; ++i) {
      xv[i] = *(const float4*)&xs[r * 260 + sub * 4 + i * 32];
      sx  += xv[i].x + xv[i].y + xv[i].z + xv[i].w;
      sxx += xv[i].x * xv[i].x + xv[i].y * xv[i].y + xv[i].z * xv[i].z +
             xv[i].w * xv[i].w;
    }
#pragma unroll
    for (int d = 1; d < 8; d <<= 1) {
      sx  += __shfl_xor(sx, d, 64);
      sxx += __shfl_xor(sxx, d, 64);
    }
    float mu = sx * (1.0f / 256.0f);
    float rstd = rsqrtf(sxx * (1.0f / 256.0f) - mu * mu + 1e-5f);
#pragma unroll
    for (int i = 0; i < 8; ++i) {
      int c = sub * 4 + i * 32;
      float4 wv = *(const float4*)(w2 + c);
      float4 bv = *(const float4*)(b2 + c);
      unsigned short y0 = f2bf((xv[i].x - mu) * rstd * wv.x + bv.x);
      unsigned short y1 = f2bf((xv[i].y - mu) * rstd * wv.y + bv.y);
      unsigned short y2 = f2bf((xv[i].z - mu) * rstd * wv.z + bv.z);
      unsigned short y3 = f2bf((xv[i].w - mu) * rstd * wv.w + bv.w);
      uint2 ov;
      ov.x = ((unsigned int)y1 << 16) | y0;
      ov.y = ((unsigned int)y3 << 16) | y2;
      *(uint2*)(yln + (size_t)(bm + r) * 256 + c) = ov;
    }
  } else {
#pragma unroll
    for (int mi = 0; mi < 4; ++mi) {
#pragma unroll
      for (int ni = 0; ni < 2; ++ni) {
        int col = bn + w * 32 + ni * 16 + lr;
        float bv = bias[col];
#pragma unroll
        for (int j = 0; j < 4; ++j) {
          int rg = bm + mi * 16 + lk * 4 + j;
          float x = acc[mi][ni][j] + bv;
          if constexpr (EPI == 0) {
            if (col < 256) {
              ((unsigned short*)o1)[(size_t)rg * 256 + col] = f2bf(x * kScale);
            } else {
              int c = col - 256;
              int h = c >> 6, sbit = (c >> 5) & 1, ch = c & 31;
              unsigned short* dst = sbit ? o3 : o2;
              dst[(size_t)rg * 256 + h * 32 + ch] = f2bf(x);
            }
          } else if constexpr (EPI == 2) {
            float g = 0.5f * x * (1.0f + erff(x * 0.70710678118654752f));
            ((unsigned short*)o1)[(size_t)rg * 512 + col] = f2bf(g);
          } else {
            ((float*)o1)[(size_t)rg * 256 + col] =
                res[(size_t)rg * 256 + col] + x;
          }
        }
      }
    }
  }
#undef STAGE_T
}

// -------- Attention: (batch x head-pair) -> XCD partition, lean inner loops --
// bid&7 -> partition (b = p>>2, hg = p&3). Wave = one (token, head-pair).
// Stage: lane l converts ONE q value (bf16->f32) into LDS; member byte-offsets
// precomputed in LDS. QK: lane (hloc=l>>5, m=l&31) -> logit, q via broadcast
// ds_read_b128. Blank: per-lane single product + shfl reduce. Softmax: shfl
// within 32-lane half. PV: lane (hp, sq=(l>>3)&3, c8=l&7) -> 4 ch x 8 members
// (uint2 loads), combined via shfl_xor(8,16).
__global__ __launch_bounds__(256) void attn_kernel(
    const unsigned short* __restrict__ q, const unsigned short* __restrict__ k,
    const unsigned short* __restrict__ v, const int* __restrict__ member_idx,
    const int* __restrict__ pe_idx, const float* __restrict__ cmask,
    const float* __restrict__ pe_full, const float* __restrict__ blank_k,
    const float* __restrict__ blank_v, unsigned short* __restrict__ outp) {
  int t = threadIdx.x;
  int w = t >> 6, l = t & 63;
  int bid = blockIdx.x;
  int part = bid & 7;
  int bb = part >> 2, hg = part & 3;
  int row = bb * kN + (bid >> 3) * 4 + w;
  const unsigned int kvbyte = (unsigned int)bb * (kN * 512u);
  const int hloc = l >> 5, m = l & 31;
  const int head = hg * 2 + hloc;

  __shared__ float        qs[4][64];        // f32 q, [wave][hg*64 channel]
  __shared__ float        aw[4][2][34];     // attn weights + blank at [32]
  __shared__ unsigned int offs[4][32];      // member byte offsets

  // ---- stage: 1 q value per lane; byte offsets for members ----
  qs[w][l] = bflo((unsigned int)q[(size_t)row * 256 + hg * 64 + l]);
  int   idxv = member_idx[(size_t)row * 32 + m];
  float mk   = (1.0f - cmask[(size_t)row * 32 + m]) * -100.0f;
  float pe   = pe_full[(size_t)pe_idx[(size_t)row * 32 + m] * 8 + head];
  if (l < 32) offs[w][l] = kvbyte + (unsigned int)idxv * 512u;
  __syncthreads();

  // ---- q fragment from LDS (broadcast within half) ----
  float4 qv[8];
#pragma unroll
  for (int i = 0; i < 8; ++i) qv[i] = *(const float4*)&qs[w][hloc * 32 + i * 4];

  // ---- QK logit: 64B K slice per lane ----
  unsigned int koff = kvbyte + (unsigned int)idxv * 512u;
  const char* kp = (const char*)k + koff + head * 64;
  float lg = 0.f;
#pragma unroll
  for (int j = 0; j < 4; ++j) {
    uint4 u = *(const uint4*)(kp + j * 16);
    lg = fmaf(qv[2 * j].x, bflo(u.x), lg);
    lg = fmaf(qv[2 * j].y, bfhi(u.x), lg);
    lg = fmaf(qv[2 * j].z, bflo(u.y), lg);
    lg = fmaf(qv[2 * j].w, bfhi(u.y), lg);
    lg = fmaf(qv[2 * j + 1].x, bflo(u.z), lg);
    lg = fmaf(qv[2 * j + 1].y, bfhi(u.z), lg);
    lg = fmaf(qv[2 * j + 1].z, bflo(u.w), lg);
    lg = fmaf(qv[2 * j + 1].w, bfhi(u.w), lg);
  }
  lg += mk + pe;

  // ---- blank logit: per-lane single product + 5-step reduce ----
  float bl = qs[w][hloc * 32 + m] * blank_k[head * 32 + m];
#pragma unroll
  for (int d = 1; d < 32; d <<= 1) bl += __shfl_xor(bl, d, 64);
  bl = fminf(fmaxf(bl, -5.0f), 5.0f);

  // ---- softmax over 33 within the 32-lane half ----
  float mx = lg;
#pragma unroll
  for (int d = 1; d < 32; d <<= 1) mx = fmaxf(mx, __shfl_xor(mx, d, 64));
  mx = fmaxf(mx, bl);
  float e = __expf(lg - mx);
  float s = e;
#pragma unroll
  for (int d = 1; d < 32; d <<= 1) s += __shfl_xor(s, d, 64);
  float eb = __expf(bl - mx);
  s += eb;
  float inv = __builtin_amdgcn_rcpf(s);
  aw[w][hloc][m] = e * inv;
  if (m == 0) aw[w][hloc][32] = eb * inv;
  __syncthreads();

  // ---- PV: lane (hp, sq, c8) -> channels c8*4..+3, members sq*8..+7 ----
  const int hp = l >> 5, sq = (l >> 3) & 3, c8 = l & 7;
  const char* vb = (const char*)v + (hg * 2 + hp) * 64 + c8 * 8;
  float a0 = 0.f, a1 = 0.f, a2 = 0.f, a3 = 0.f;
#pragma unroll
  for (int i = 0; i < 8; ++i) {
    int mm = sq * 8 + i;
    float a = aw[w][hp][mm];
    uint2 u = *(const uint2*)(vb + offs[w][mm]);
    a0 = fmaf(a, bflo(u.x), a0);
    a1 = fmaf(a, bfhi(u.x), a1);
    a2 = fmaf(a, bflo(u.y), a2);
    a3 = fmaf(a, bfhi(u.y), a3);
  }
  a0 += __shfl_xor(a0, 8, 64);  a1 += __shfl_xor(a1, 8, 64);
  a2 += __shfl_xor(a2, 8, 64);  a3 += __shfl_xor(a3, 8, 64);
  a0 += __shfl_xor(a0, 16, 64); a1 += __shfl_xor(a1, 16, 64);
  a2 += __shfl_xor(a2, 16, 64); a3 += __shfl_xor(a3, 16, 64);
  if (sq == 0) {
    float ab = aw[w][hp][32];
    int c = (hg * 2 + hp) * 32 + c8 * 4;
    float4 bv = *(const float4*)(blank_v + c);
    a0 = fmaf(ab, bv.x, a0);
    a1 = fmaf(ab, bv.y, a1);
    a2 = fmaf(ab, bv.z, a2);
    a3 = fmaf(ab, bv.w, a3);
    uint2 o;
    o.x = ((unsigned int)f2bf(a1) << 16) | f2bf(a0);
    o.y = ((unsigned int)f2bf(a3) << 16) | f2bf(a2);
    *(uint2*)(outp + (size_t)row * 256 + c) = o;
  }
}

extern "C" void kernel_launch(void* const* d_in, const int* in_sizes, int n_in,
                              void* d_out, int out_size, void* d_ws, size_t ws_size,
                              hipStream_t stream) {
  const float* feat       = (const float*)d_in[0];
  const int*   member_idx = (const int*)d_in[1];
  const float* cmask      = (const float*)d_in[2];
  const int*   pe_idx     = (const int*)d_in[3];
  const float* pre_table  = (const float*)d_in[5];
  const float* n1w        = (const float*)d_in[6];
  const float* n1b        = (const float*)d_in[7];
  const float* q_w        = (const float*)d_in[8];
  const float* q_b        = (const float*)d_in[9];
  const float* kv_w       = (const float*)d_in[10];
  const float* kv_b       = (const float*)d_in[11];
  const float* blank_k    = (const float*)d_in[12];
  const float* blank_v    = (const float*)d_in[13];
  const float* pe_w       = (const float*)d_in[14];
  const float* pe_b       = (const float*)d_in[15];
  const float* proj_w     = (const float*)d_in[16];
  const float* proj_b     = (const float*)d_in[17];
  const float* n2w        = (const float*)d_in[18];
  const float* n2b        = (const float*)d_in[19];
  const float* fc1_w      = (const float*)d_in[20];
  const float* fc1_b      = (const float*)d_in[21];
  const float* fc2_w      = (const float*)d_in[22];
  const float* fc2_b      = (const float*)d_in[23];

  float* out = (float*)d_out;
  unsigned char* ws = (unsigned char*)d_ws;

  unsigned short* xln   = (unsigned short*)(ws + 0);           // 8 MB, later attn_out
  unsigned short* q_buf = (unsigned short*)(ws + 8388608);     // 8 MB, later yln
  unsigned short* k_buf = (unsigned short*)(ws + 16777216);    // 8 MB \ later h1 (16MB)
  unsigned short* v_buf = (unsigned short*)(ws + 25165824);    // 8 MB /
  unsigned short* wqkv  = (unsigned short*)(ws + 33554432);    // 384 KB
  unsigned short* wproj = (unsigned short*)(ws + 33947648);    // 128 KB
  unsigned short* wfc1  = (unsigned short*)(ws + 34078720);    // 256 KB
  unsigned short* wfc2  = (unsigned short*)(ws + 34340864);    // 256 KB
  float*          bqkv  = (float*)(ws + 34603008);             // 3 KB
  float*          pe_buf= (float*)(ws + 34606080);             // ~97 KB
  unsigned short* attn_out = xln;
  unsigned short* yln   = q_buf;
  unsigned short* h1    = k_buf;   // 16 MB spanning k_buf+v_buf

  cast_weights_kernel<<<2052, 256, 0, stream>>>(
      q_w, kv_w, proj_w, fc1_w, fc2_w, q_b, kv_b, wqkv, wproj, wfc1, wfc2, bqkv);
  pe_kernel<<<(kTAB * 8 + 255) / 256, 256, 0, stream>>>(pre_table, pe_w, pe_b, pe_buf);
  ln_bf16_kernel<<<kRowsTotal / 4, 256, 0, stream>>>(feat, n1w, n1b, xln);

  gemm64<0, 256><<<dim3(kRowsTotal / 64, 3), 512, 0, stream>>>(
      xln, wqkv, bqkv, q_buf, k_buf, v_buf, nullptr, nullptr, nullptr, nullptr);

  attn_kernel<<<kRowsTotal, 256, 0, stream>>>(
      q_buf, k_buf, v_buf, member_idx, pe_idx, cmask, pe_buf, blank_k, blank_v,
      attn_out);

  gemm64<1, 256><<<dim3(kRowsTotal / 64, 1), 512, 0, stream>>>(
      attn_out, wproj, proj_b, out, nullptr, nullptr, feat, n2w, n2b, yln);

  gemm64<2, 256><<<dim3(kRowsTotal / 64, 2), 512, 0, stream>>>(
      yln, wfc1, fc1_b, h1, nullptr, nullptr, nullptr, nullptr, nullptr, nullptr);

  gemm64<3, 512><<<dim3(kRowsTotal / 64, 1), 512, 0, stream>>>(
      h1, wfc2, fc2_b, out, nullptr, nullptr, out, nullptr, nullptr, nullptr);
}

// Round 12
// 130.428 us; speedup vs baseline: 1.1221x; 1.0052x over previous
//
#include <hip/hip_runtime.h>
#include <math.h>

namespace {
constexpr int kN    = 8192;
constexpr int kC    = 256;
constexpr int kTAB  = 3025;
constexpr int kRowsTotal = 2 * kN;  // B*N = 16384
constexpr float kScale = 0.17677669529663687f;  // 32^-0.5
}

typedef __attribute__((ext_vector_type(8))) short bf16x8;
typedef __attribute__((ext_vector_type(4))) float f32x4;

__device__ __forceinline__ unsigned short f2bf(float f) {
  unsigned int u = __float_as_uint(f);
  u += 0x7fffu + ((u >> 16) & 1u);   // round-to-nearest-even
  return (unsigned short)(u >> 16);
}
__device__ __forceinline__ float bflo(unsigned int u) {
  return __uint_as_float(u << 16);
}
__device__ __forceinline__ float bfhi(unsigned int u) {
  return __uint_as_float(u & 0xffff0000u);
}

#define GLOAD16(g, l)                                                   \
  __builtin_amdgcn_global_load_lds(                                     \
      (const __attribute__((address_space(1))) void*)(g),               \
      (__attribute__((address_space(3))) void*)(l), 16, 0, 0)

// ---------------- LayerNorm -> bf16 (wave per row, no barriers) --------------
__global__ __launch_bounds__(256) void ln_bf16_kernel(
    const float* __restrict__ x, const float* __restrict__ w,
    const float* __restrict__ b, unsigned short* __restrict__ o) {
  int t = threadIdx.x;
  int row = blockIdx.x * 4 + (t >> 6);
  int l = t & 63;
  float4 v = *(const float4*)(x + (size_t)row * kC + l * 4);
  float s  = v.x + v.y + v.z + v.w;
  float s2 = v.x * v.x + v.y * v.y + v.z * v.z + v.w * v.w;
#pragma unroll
  for (int d = 1; d < 64; d <<= 1) {
    s  += __shfl_xor(s, d, 64);
    s2 += __shfl_xor(s2, d, 64);
  }
  float mu = s * (1.0f / kC);
  float rstd = rsqrtf(s2 * (1.0f / kC) - mu * mu + 1e-5f);
  float4 wv = *(const float4*)(w + l * 4);
  float4 bv = *(const float4*)(b + l * 4);
  unsigned short o0 = f2bf((v.x - mu) * rstd * wv.x + bv.x);
  unsigned short o1 = f2bf((v.y - mu) * rstd * wv.y + bv.y);
  unsigned short o2 = f2bf((v.z - mu) * rstd * wv.z + bv.z);
  unsigned short o3 = f2bf((v.w - mu) * rstd * wv.w + bv.w);
  uint2 ov;
  ov.x = ((unsigned int)o1 << 16) | o0;
  ov.y = ((unsigned int)o3 << 16) | o2;
  *(uint2*)(o + (size_t)row * kC + l * 4) = ov;
}

// ---------------- PE table: pe_full[tab][8] f32 ----------------
__global__ __launch_bounds__(256) void pe_kernel(const float* __restrict__ tab,
                                                 const float* __restrict__ pw,
                                                 const float* __restrict__ pb,
                                                 float* __restrict__ outp) {
  int i = blockIdx.x * 256 + threadIdx.x;
  if (i >= kTAB * 8) return;
  int r = i >> 3, h = i & 7;
  float acc = pb[h];
#pragma unroll
  for (int f = 0; f < 5; ++f) acc += tab[r * 5 + f] * pw[h * 5 + f];
  outp[i] = acc;
}

// -------- pos precompute: pos_buf[row][head][m] = pe_full[pe_idx[row][m]][h] --
// thread i: row = i>>8, m = (i>>3)&31, h = i&7 -> 8 consecutive threads read
// one 32B pe_full entry (coalesced); writes land within 1KB per row.
__global__ __launch_bounds__(256) void pos_precompute_kernel(
    const int* __restrict__ pe_idx, const float* __restrict__ pe_full,
    float* __restrict__ pos_buf) {
  int i = blockIdx.x * 256 + threadIdx.x;
  int row = i >> 8, m = (i >> 3) & 31, h = i & 7;
  int idx = pe_idx[(size_t)row * 32 + m];
  pos_buf[(size_t)row * 256 + h * 32 + m] = pe_full[(size_t)idx * 8 + h];
}

// ---------------- cast weights to bf16 (+ concat qkv bias) ----------------
__global__ __launch_bounds__(256) void cast_weights_kernel(
    const float* __restrict__ qw, const float* __restrict__ kvw,
    const float* __restrict__ pjw, const float* __restrict__ f1w,
    const float* __restrict__ f2w, const float* __restrict__ qb,
    const float* __restrict__ kvb, unsigned short* __restrict__ wqkv,
    unsigned short* __restrict__ wproj, unsigned short* __restrict__ wfc1,
    unsigned short* __restrict__ wfc2, float* __restrict__ bqkv) {
  int i = blockIdx.x * 256 + threadIdx.x;
  if (i < 65536)       wqkv[i]            = f2bf(qw[i]);
  else if (i < 196608) wqkv[i]            = f2bf(kvw[i - 65536]);
  else if (i < 262144) wproj[i - 196608]  = f2bf(pjw[i - 196608]);
  else if (i < 393216) wfc1[i - 262144]   = f2bf(f1w[i - 262144]);
  else if (i < 524288) wfc2[i - 393216]   = f2bf(f2w[i - 393216]);
  else if (i < 524544) bqkv[i - 524288]   = qb[i - 524288];
  else if (i < 525056) bqkv[i - 524288]   = kvb[i - 524544];
}

// ---- bf16 MFMA GEMM: BM=64, BN=256, 8 waves (512 thr), BK=64 double-buffer --
template <int EPI, int KDIM>
__global__ __launch_bounds__(512) void gemm64(
    const unsigned short* __restrict__ A, const unsigned short* __restrict__ Wt,
    const float* __restrict__ bias, void* __restrict__ o1,
    unsigned short* __restrict__ o2, unsigned short* __restrict__ o3,
    const float* __restrict__ res, const float* __restrict__ w2,
    const float* __restrict__ b2, unsigned short* __restrict__ yln) {
  __shared__ alignas(16) unsigned short smem[40960];
  unsigned short* As0 = smem;
  unsigned short* Bs0 = smem + 8192;
  int t = threadIdx.x;
  int w = t >> 6, l = t & 63;
  int bm = blockIdx.x * 64, bn = blockIdx.y * 256;

  f32x4 acc[4][2] = {};

  const size_t aoff = (size_t)(bm + w * 8 + (l >> 3)) * KDIM + (l & 7) * 8;
  const size_t boff = (size_t)(bn + w * 32 + (l >> 3)) * KDIM + (l & 7) * 8;
  const int lr = l & 15, lk = l >> 4;

#define STAGE_T(buf, k0)                                                      \
  do {                                                                        \
    GLOAD16(A + aoff + (k0), As0 + (buf)*4096 + w * 512 + l * 8);             \
    GLOAD16(Wt + boff + (k0), Bs0 + (buf)*16384 + w * 2048 + l * 8);          \
    GLOAD16(Wt + boff + (k0) + (size_t)8 * KDIM,                              \
            Bs0 + (buf)*16384 + w * 2048 + 512 + l * 8);                      \
    GLOAD16(Wt + boff + (k0) + (size_t)16 * KDIM,                             \
            Bs0 + (buf)*16384 + w * 2048 + 1024 + l * 8);                     \
    GLOAD16(Wt + boff + (k0) + (size_t)24 * KDIM,                             \
            Bs0 + (buf)*16384 + w * 2048 + 1536 + l * 8);                     \
  } while (0)

  auto compute = [&](int buf) {
#pragma unroll
    for (int kk = 0; kk < 2; ++kk) {
      bf16x8 af[4], bfr[2];
#pragma unroll
      for (int mi = 0; mi < 4; ++mi)
        af[mi] = *(const bf16x8*)(As0 + buf * 4096 + (mi * 16 + lr) * 64 +
                                  kk * 32 + lk * 8);
#pragma unroll
      for (int ni = 0; ni < 2; ++ni)
        bfr[ni] = *(const bf16x8*)(Bs0 + buf * 16384 +
                                   (w * 32 + ni * 16 + lr) * 64 + kk * 32 +
                                   lk * 8);
#pragma unroll
      for (int mi = 0; mi < 4; ++mi)
#pragma unroll
        for (int ni = 0; ni < 2; ++ni)
          acc[mi][ni] = __builtin_amdgcn_mfma_f32_16x16x32_bf16(
              af[mi], bfr[ni], acc[mi][ni], 0, 0, 0);
    }
  };

  STAGE_T(0, 0);
  __syncthreads();
  int cur = 0;
#pragma unroll
  for (int k0 = 64; k0 < KDIM; k0 += 64) {
    STAGE_T(cur ^ 1, k0);
    compute(cur);
    __syncthreads();
    cur ^= 1;
  }
  compute(cur);

  if constexpr (EPI == 1) {
    __syncthreads();
    float* xs = (float*)smem;
#pragma unroll
    for (int mi = 0; mi < 4; ++mi) {
#pragma unroll
      for (int ni = 0; ni < 2; ++ni) {
        int c = w * 32 + ni * 16 + lr;
        float bv = bias[c];
#pragma unroll
        for (int j = 0; j < 4; ++j) {
          int rl = mi * 16 + lk * 4 + j;
          float x = acc[mi][ni][j] + bv + res[(size_t)(bm + rl) * 256 + c];
          xs[rl * 260 + c] = x;
          ((float*)o1)[(size_t)(bm + rl) * 256 + c] = x;
        }
      }
    }
    __syncthreads();
    int r = t >> 3, sub = t & 7;
    float4 xv[8];
    float sx = 0.f, sxx = 0.f;
#pragma unroll
    for (int i = 0; i < 8; ++i) {
      xv[i] = *(const float4*)&xs[r * 260 + sub * 4 + i * 32];
      sx  += xv[i].x + xv[i].y + xv[i].z + xv[i].w;
      sxx += xv[i].x * xv[i].x + xv[i].y * xv[i].y + xv[i].z * xv[i].z +
             xv[i].w * xv[i].w;
    }
#pragma unroll
    for (int d = 1; d < 8; d <<= 1) {
      sx  += __shfl_xor(sx, d, 64);
      sxx += __shfl_xor(sxx, d, 64);
    }
    float mu = sx * (1.0f / 256.0f);
    float rstd = rsqrtf(sxx * (1.0f / 256.0f) - mu * mu + 1e-5f);
#pragma unroll
    for (int i = 0; i < 8; ++i) {
      int c = sub * 4 + i * 32;
      float4 wv = *(const float4*)(w2 + c);
      float4 bv = *(const float4*)(b2 + c);
      unsigned short y0 = f2bf((xv[i].x - mu) * rstd * wv.x + bv.x);
      unsigned short y1 = f2bf((xv[i].y - mu) * rstd * wv.y + bv.y);
      unsigned short y2 = f2bf((xv[i].z - mu) * rstd * wv.z + bv.z);
      unsigned short y3 = f2bf((xv[i].w - mu) * rstd * wv.w + bv.w);
      uint2 ov;
      ov.x = ((unsigned int)y1 << 16) | y0;
      ov.y = ((unsigned int)y3 << 16) | y2;
      *(uint2*)(yln + (size_t)(bm + r) * 256 + c) = ov;
    }
  } else {
#pragma unroll
    for (int mi = 0; mi < 4; ++mi) {
#pragma unroll
      for (int ni = 0; ni < 2; ++ni) {
        int col = bn + w * 32 + ni * 16 + lr;
        float bv = bias[col];
#pragma unroll
        for (int j = 0; j < 4; ++j) {
          int rg = bm + mi * 16 + lk * 4 + j;
          float x = acc[mi][ni][j] + bv;
          if constexpr (EPI == 0) {
            if (col < 256) {
              ((unsigned short*)o1)[(size_t)rg * 256 + col] = f2bf(x * kScale);
            } else {
              int c = col - 256;
              int h = c >> 6, sbit = (c >> 5) & 1, ch = c & 31;
              unsigned short* dst = sbit ? o3 : o2;
              dst[(size_t)rg * 256 + h * 32 + ch] = f2bf(x);
            }
          } else if constexpr (EPI == 2) {
            float g = 0.5f * x * (1.0f + erff(x * 0.70710678118654752f));
            ((unsigned short*)o1)[(size_t)rg * 512 + col] = f2bf(g);
          } else {
            ((float*)o1)[(size_t)rg * 256 + col] =
                res[(size_t)rg * 256 + col] + x;
          }
        }
      }
    }
  }
#undef STAGE_T
}

// -------- Attention: XCD-partitioned, line-coalesced gathers ------------------
// bid&7 -> partition (b = p>>2, hg = p&3). Wave = one (token, head-pair).
// QK: lane (m8=l>>3, ch=l&7); 8 lanes read one member's 128B head-pair slice
// contiguously (16 line-reqs/instr). Partial dot (8ch) -> shfl_xor(1,2) per
// member/head; softmax over members via shfl_xor(8,16,32) (ch preserved ->
// heads stay separate). pos bias from precomputed pos_buf (f32, coalesced).
// PV: lane (hp=l>>5, sq, c8); 8 lanes/row = 64B contiguous (optimal lines).
__global__ __launch_bounds__(256) void attn_kernel(
    const unsigned short* __restrict__ q, const unsigned short* __restrict__ k,
    const unsigned short* __restrict__ v, const int* __restrict__ member_idx,
    const float* __restrict__ cmask, const float* __restrict__ pos_buf,
    const float* __restrict__ blank_k, const float* __restrict__ blank_v,
    unsigned short* __restrict__ outp) {
  int t = threadIdx.x;
  int w = t >> 6, l = t & 63;
  int bid = blockIdx.x;
  int part = bid & 7;
  int bb = part >> 2, hg = part & 3;
  int row = bb * kN + (bid >> 3) * 4 + w;
  const unsigned int kvbyte = (unsigned int)bb * (kN * 512u);

  __shared__ float        qs[4][64];       // head-pair q slice, f32
  __shared__ float        aw[4][2][36];    // weights + blank at [32]
  __shared__ unsigned int offs[4][32];     // member K/V row byte offsets
  __shared__ float        mkl[4][32];      // mask bias
  __shared__ float        posl[4][2][32];  // pos bias [hloc][m]

  // ---- stage ----
  {
    int m = l & 31, hloc = l >> 5;
    qs[w][l] = bflo((unsigned int)q[(size_t)row * 256 + hg * 64 + l]);
    posl[w][hloc][m] =
        pos_buf[(size_t)row * 256 + (hg * 2 + hloc) * 32 + m];
    if (l < 32) {
      offs[w][l] = kvbyte + (unsigned int)member_idx[(size_t)row * 32 + l] * 512u;
      mkl[w][l]  = (1.0f - cmask[(size_t)row * 32 + l]) * -100.0f;
    }
  }
  __syncthreads();

  const int m8 = l >> 3, ch = l & 7;
  const int hsel = ch >> 2;   // which head of the pair this lane's channels hit

  // per-lane q fragment: channels [ch*8, ch*8+8) of the 64-ch head-pair slice
  float qv[8];
  {
    float4 a = *(const float4*)&qs[w][ch * 8];
    float4 b = *(const float4*)&qs[w][ch * 8 + 4];
    qv[0] = a.x; qv[1] = a.y; qv[2] = a.z; qv[3] = a.w;
    qv[4] = b.x; qv[5] = b.y; qv[6] = b.z; qv[7] = b.w;
  }

  // ---- QK: 4 coalesced instructions, partial-dot + 2-step reduce ----
  float lg[4];
#pragma unroll
  for (int i = 0; i < 4; ++i) {
    int mi = i * 8 + m8;
    const char* kp = (const char*)k + offs[w][mi] + hg * 128 + ch * 16;
    uint4 u = *(const uint4*)kp;
    float p = 0.f;
    p = fmaf(qv[0], bflo(u.x), p);
    p = fmaf(qv[1], bfhi(u.x), p);
    p = fmaf(qv[2], bflo(u.y), p);
    p = fmaf(qv[3], bfhi(u.y), p);
    p = fmaf(qv[4], bflo(u.z), p);
    p = fmaf(qv[5], bfhi(u.z), p);
    p = fmaf(qv[6], bflo(u.w), p);
    p = fmaf(qv[7], bfhi(u.w), p);
    p += __shfl_xor(p, 1, 64);
    p += __shfl_xor(p, 2, 64);
    lg[i] = p + mkl[w][mi] + posl[w][hsel][mi];
  }

  // ---- blank logit for this lane's head ----
  float bl = 0.f;
  {
    const float* bk = blank_k + hg * 64 + ch * 8;
#pragma unroll
    for (int e = 0; e < 8; ++e) bl = fmaf(qv[e], bk[e], bl);
    bl += __shfl_xor(bl, 1, 64);
    bl += __shfl_xor(bl, 2, 64);
    bl = fminf(fmaxf(bl, -5.0f), 5.0f);
  }

  // ---- softmax over 33 per head (ch-preserving member reduce) ----
  float mx = fmaxf(fmaxf(lg[0], lg[1]), fmaxf(lg[2], lg[3]));
  mx = fmaxf(mx, __shfl_xor(mx, 8, 64));
  mx = fmaxf(mx, __shfl_xor(mx, 16, 64));
  mx = fmaxf(mx, __shfl_xor(mx, 32, 64));
  mx = fmaxf(mx, bl);
  float e4[4], s = 0.f;
#pragma unroll
  for (int i = 0; i < 4; ++i) { e4[i] = __expf(lg[i] - mx); s += e4[i]; }
  s += __shfl_xor(s, 8, 64);
  s += __shfl_xor(s, 16, 64);
  s += __shfl_xor(s, 32, 64);
  float eb = __expf(bl - mx);
  s += eb;
  float inv = __builtin_amdgcn_rcpf(s);
  if ((ch & 3) == 0) {
#pragma unroll
    for (int i = 0; i < 4; ++i) aw[w][hsel][i * 8 + m8] = e4[i] * inv;
    if (m8 == 0) aw[w][hsel][32] = eb * inv;
  }
  __syncthreads();

  // ---- PV: lane (hp, sq, c8) -> channels c8*4..+3, members sq*8..+7 ----
  const int hp = l >> 5, sq = (l >> 3) & 3, c8 = l & 7;
  const char* vb = (const char*)v + (hg * 2 + hp) * 64 + c8 * 8;
  float a0 = 0.f, a1 = 0.f, a2 = 0.f, a3 = 0.f;
#pragma unroll
  for (int i = 0; i < 8; ++i) {
    int mm = sq * 8 + i;
    float a = aw[w][hp][mm];
    uint2 u = *(const uint2*)(vb + offs[w][mm]);
    a0 = fmaf(a, bflo(u.x), a0);
    a1 = fmaf(a, bfhi(u.x), a1);
    a2 = fmaf(a, bflo(u.y), a2);
    a3 = fmaf(a, bfhi(u.y), a3);
  }
  a0 += __shfl_xor(a0, 8, 64);  a1 += __shfl_xor(a1, 8, 64);
  a2 += __shfl_xor(a2, 8, 64);  a3 += __shfl_xor(a3, 8, 64);
  a0 += __shfl_xor(a0, 16, 64); a1 += __shfl_xor(a1, 16, 64);
  a2 += __shfl_xor(a2, 16, 64); a3 += __shfl_xor(a3, 16, 64);
  if (sq == 0) {
    float ab = aw[w][hp][32];
    int c = (hg * 2 + hp) * 32 + c8 * 4;
    float4 bv = *(const float4*)(blank_v + c);
    a0 = fmaf(ab, bv.x, a0);
    a1 = fmaf(ab, bv.y, a1);
    a2 = fmaf(ab, bv.z, a2);
    a3 = fmaf(ab, bv.w, a3);
    uint2 o;
    o.x = ((unsigned int)f2bf(a1) << 16) | f2bf(a0);
    o.y = ((unsigned int)f2bf(a3) << 16) | f2bf(a2);
    *(uint2*)(outp + (size_t)row * 256 + c) = o;
  }
}

extern "C" void kernel_launch(void* const* d_in, const int* in_sizes, int n_in,
                              void* d_out, int out_size, void* d_ws, size_t ws_size,
                              hipStream_t stream) {
  const float* feat       = (const float*)d_in[0];
  const int*   member_idx = (const int*)d_in[1];
  const float* cmask      = (const float*)d_in[2];
  const int*   pe_idx     = (const int*)d_in[3];
  const float* pre_table  = (const float*)d_in[5];
  const float* n1w        = (const float*)d_in[6];
  const float* n1b        = (const float*)d_in[7];
  const float* q_w        = (const float*)d_in[8];
  const float* q_b        = (const float*)d_in[9];
  const float* kv_w       = (const float*)d_in[10];
  const float* kv_b       = (const float*)d_in[11];
  const float* blank_k    = (const float*)d_in[12];
  const float* blank_v    = (const float*)d_in[13];
  const float* pe_w       = (const float*)d_in[14];
  const float* pe_b       = (const float*)d_in[15];
  const float* proj_w     = (const float*)d_in[16];
  const float* proj_b     = (const float*)d_in[17];
  const float* n2w        = (const float*)d_in[18];
  const float* n2b        = (const float*)d_in[19];
  const float* fc1_w      = (const float*)d_in[20];
  const float* fc1_b      = (const float*)d_in[21];
  const float* fc2_w      = (const float*)d_in[22];
  const float* fc2_b      = (const float*)d_in[23];

  float* out = (float*)d_out;
  unsigned char* ws = (unsigned char*)d_ws;

  unsigned short* xln   = (unsigned short*)(ws + 0);           // 8 MB, later attn_out
  unsigned short* q_buf = (unsigned short*)(ws + 8388608);     // 8 MB, later yln
  unsigned short* k_buf = (unsigned short*)(ws + 16777216);    // 8 MB \ later h1 (16MB)
  unsigned short* v_buf = (unsigned short*)(ws + 25165824);    // 8 MB /
  unsigned short* wqkv  = (unsigned short*)(ws + 33554432);    // 384 KB
  unsigned short* wproj = (unsigned short*)(ws + 33947648);    // 128 KB
  unsigned short* wfc1  = (unsigned short*)(ws + 34078720);    // 256 KB
  unsigned short* wfc2  = (unsigned short*)(ws + 34340864);    // 256 KB
  float*          bqkv  = (float*)(ws + 34603008);             // 3 KB
  float*          pe_buf= (float*)(ws + 34606080);             // ~97 KB
  unsigned short* attn_out = xln;
  unsigned short* yln   = q_buf;
  unsigned short* h1    = k_buf;   // 16 MB spanning k_buf+v_buf
  float*          pos_buf = out;   // d_out dead until proj: 16 MB f32 scratch

  cast_weights_kernel<<<2052, 256, 0, stream>>>(
      q_w, kv_w, proj_w, fc1_w, fc2_w, q_b, kv_b, wqkv, wproj, wfc1, wfc2, bqkv);
  pe_kernel<<<(kTAB * 8 + 255) / 256, 256, 0, stream>>>(pre_table, pe_w, pe_b, pe_buf);
  ln_bf16_kernel<<<kRowsTotal / 4, 256, 0, stream>>>(feat, n1w, n1b, xln);
  pos_precompute_kernel<<<kRowsTotal, 256, 0, stream>>>(pe_idx, pe_buf, pos_buf);

  gemm64<0, 256><<<dim3(kRowsTotal / 64, 3), 512, 0, stream>>>(
      xln, wqkv, bqkv, q_buf, k_buf, v_buf, nullptr, nullptr, nullptr, nullptr);

  attn_kernel<<<kRowsTotal, 256, 0, stream>>>(
      q_buf, k_buf, v_buf, member_idx, cmask, pos_buf, blank_k, blank_v,
      attn_out);

  gemm64<1, 256><<<dim3(kRowsTotal / 64, 1), 512, 0, stream>>>(
      attn_out, wproj, proj_b, out, nullptr, nullptr, feat, n2w, n2b, yln);

  gemm64<2, 256><<<dim3(kRowsTotal / 64, 2), 512, 0, stream>>>(
      yln, wfc1, fc1_b, h1, nullptr, nullptr, nullptr, nullptr, nullptr, nullptr);

  gemm64<3, 512><<<dim3(kRowsTotal / 64, 1), 512, 0, stream>>>(
      h1, wfc2, fc2_b, out, nullptr, nullptr, out, nullptr, nullptr, nullptr);
}

// Round 13
// 124.231 us; speedup vs baseline: 1.1781x; 1.0499x over previous
//
#include <hip/hip_runtime.h>
#include <math.h>

namespace {
constexpr int kN    = 8192;
constexpr int kC    = 256;
constexpr int kTAB  = 3025;
constexpr int kRowsTotal = 2 * kN;  // B*N = 16384
constexpr float kScale = 0.17677669529663687f;  // 32^-0.5
}

typedef __attribute__((ext_vector_type(8))) short bf16x8;
typedef __attribute__((ext_vector_type(4))) float f32x4;
typedef _Float16 h8 __attribute__((ext_vector_type(8)));
typedef _Float16 h4 __attribute__((ext_vector_type(4)));

__device__ __forceinline__ unsigned short f2bf(float f) {
  unsigned int u = __float_as_uint(f);
  u += 0x7fffu + ((u >> 16) & 1u);   // round-to-nearest-even
  return (unsigned short)(u >> 16);
}
__device__ __forceinline__ float bflo(unsigned int u) {
  return __uint_as_float(u << 16);
}
__device__ __forceinline__ float bfhi(unsigned int u) {
  return __uint_as_float(u & 0xffff0000u);
}
__device__ __forceinline__ unsigned short f2h(float f) {
  _Float16 h = (_Float16)f;
  unsigned short u;
  __builtin_memcpy(&u, &h, 2);
  return u;
}
__device__ __forceinline__ float h2f(unsigned short u) {
  _Float16 h;
  __builtin_memcpy(&h, &u, 2);
  return (float)h;
}

#define GLOAD16(g, l)                                                   \
  __builtin_amdgcn_global_load_lds(                                     \
      (const __attribute__((address_space(1))) void*)(g),               \
      (__attribute__((address_space(3))) void*)(l), 16, 0, 0)

// ---------------- LayerNorm -> bf16 (wave per row, no barriers) --------------
__global__ __launch_bounds__(256) void ln_bf16_kernel(
    const float* __restrict__ x, const float* __restrict__ w,
    const float* __restrict__ b, unsigned short* __restrict__ o) {
  int t = threadIdx.x;
  int row = blockIdx.x * 4 + (t >> 6);
  int l = t & 63;
  float4 v = *(const float4*)(x + (size_t)row * kC + l * 4);
  float s  = v.x + v.y + v.z + v.w;
  float s2 = v.x * v.x + v.y * v.y + v.z * v.z + v.w * v.w;
#pragma unroll
  for (int d = 1; d < 64; d <<= 1) {
    s  += __shfl_xor(s, d, 64);
    s2 += __shfl_xor(s2, d, 64);
  }
  float mu = s * (1.0f / kC);
  float rstd = rsqrtf(s2 * (1.0f / kC) - mu * mu + 1e-5f);
  float4 wv = *(const float4*)(w + l * 4);
  float4 bv = *(const float4*)(b + l * 4);
  unsigned short o0 = f2bf((v.x - mu) * rstd * wv.x + bv.x);
  unsigned short o1 = f2bf((v.y - mu) * rstd * wv.y + bv.y);
  unsigned short o2 = f2bf((v.z - mu) * rstd * wv.z + bv.z);
  unsigned short o3 = f2bf((v.w - mu) * rstd * wv.w + bv.w);
  uint2 ov;
  ov.x = ((unsigned int)o1 << 16) | o0;
  ov.y = ((unsigned int)o3 << 16) | o2;
  *(uint2*)(o + (size_t)row * kC + l * 4) = ov;
}

// ---------------- PE table: pe_full[tab][8] f32 ----------------
__global__ __launch_bounds__(256) void pe_kernel(const float* __restrict__ tab,
                                                 const float* __restrict__ pw,
                                                 const float* __restrict__ pb,
                                                 float* __restrict__ outp) {
  int i = blockIdx.x * 256 + threadIdx.x;
  if (i >= kTAB * 8) return;
  int r = i >> 3, h = i & 7;
  float acc = pb[h];
#pragma unroll
  for (int f = 0; f < 5; ++f) acc += tab[r * 5 + f] * pw[h * 5 + f];
  outp[i] = acc;
}

// -- pos+mask precompute: posm[row][h][m] = f16(pe_full[pe_idx]] + maskbias) --
__global__ __launch_bounds__(256) void pos_precompute_kernel(
    const int* __restrict__ pe_idx, const float* __restrict__ pe_full,
    const float* __restrict__ cmask, unsigned short* __restrict__ posm) {
  int i = blockIdx.x * 256 + threadIdx.x;
  int row = i >> 8, m = (i >> 3) & 31, h = i & 7;
  int idx = pe_idx[(size_t)row * 32 + m];
  float v = pe_full[(size_t)idx * 8 + h] +
            (1.0f - cmask[(size_t)row * 32 + m]) * -100.0f;
  posm[(size_t)row * 256 + h * 32 + m] = f2h(v);
}

// ---------------- cast weights to bf16 (+ qkv bias, + blank_k f16) -----------
__global__ __launch_bounds__(256) void cast_weights_kernel(
    const float* __restrict__ qw, const float* __restrict__ kvw,
    const float* __restrict__ pjw, const float* __restrict__ f1w,
    const float* __restrict__ f2w, const float* __restrict__ qb,
    const float* __restrict__ kvb, const float* __restrict__ bk,
    unsigned short* __restrict__ wqkv, unsigned short* __restrict__ wproj,
    unsigned short* __restrict__ wfc1, unsigned short* __restrict__ wfc2,
    float* __restrict__ bqkv, unsigned short* __restrict__ bkh) {
  int i = blockIdx.x * 256 + threadIdx.x;
  if (i < 65536)       wqkv[i]            = f2bf(qw[i]);
  else if (i < 196608) wqkv[i]            = f2bf(kvw[i - 65536]);
  else if (i < 262144) wproj[i - 196608]  = f2bf(pjw[i - 196608]);
  else if (i < 393216) wfc1[i - 262144]   = f2bf(f1w[i - 262144]);
  else if (i < 524288) wfc2[i - 393216]   = f2bf(f2w[i - 393216]);
  else if (i < 524544) bqkv[i - 524288]   = qb[i - 524288];
  else if (i < 525056) bqkv[i - 524288]   = kvb[i - 524544];
  else if (i < 525312) bkh[i - 525056]    = f2h(bk[i - 525056]);
}

// ---- bf16 MFMA GEMM: BM=64, BN=256, 8 waves (512 thr), BK=64 double-buffer --
// EPI 0: QKV -> q/k/v stored as f16 (q scaled)
// EPI 1: proj + residual -> f32 + fused LN2 -> yln bf16
// EPI 2: fc1 + exact gelu -> bf16 (ld 512);  EPI 3: fc2 + residual -> f32
template <int EPI, int KDIM>
__global__ __launch_bounds__(512) void gemm64(
    const unsigned short* __restrict__ A, const unsigned short* __restrict__ Wt,
    const float* __restrict__ bias, void* __restrict__ o1,
    unsigned short* __restrict__ o2, unsigned short* __restrict__ o3,
    const float* __restrict__ res, const float* __restrict__ w2,
    const float* __restrict__ b2, unsigned short* __restrict__ yln) {
  __shared__ alignas(16) unsigned short smem[40960];
  unsigned short* As0 = smem;
  unsigned short* Bs0 = smem + 8192;
  int t = threadIdx.x;
  int w = t >> 6, l = t & 63;
  int bm = blockIdx.x * 64, bn = blockIdx.y * 256;

  f32x4 acc[4][2] = {};

  const size_t aoff = (size_t)(bm + w * 8 + (l >> 3)) * KDIM + (l & 7) * 8;
  const size_t boff = (size_t)(bn + w * 32 + (l >> 3)) * KDIM + (l & 7) * 8;
  const int lr = l & 15, lk = l >> 4;

#define STAGE_T(buf, k0)                                                      \
  do {                                                                        \
    GLOAD16(A + aoff + (k0), As0 + (buf)*4096 + w * 512 + l * 8);             \
    GLOAD16(Wt + boff + (k0), Bs0 + (buf)*16384 + w * 2048 + l * 8);          \
    GLOAD16(Wt + boff + (k0) + (size_t)8 * KDIM,                              \
            Bs0 + (buf)*16384 + w * 2048 + 512 + l * 8);                      \
    GLOAD16(Wt + boff + (k0) + (size_t)16 * KDIM,                             \
            Bs0 + (buf)*16384 + w * 2048 + 1024 + l * 8);                     \
    GLOAD16(Wt + boff + (k0) + (size_t)24 * KDIM,                             \
            Bs0 + (buf)*16384 + w * 2048 + 1536 + l * 8);                     \
  } while (0)

  auto compute = [&](int buf) {
#pragma unroll
    for (int kk = 0; kk < 2; ++kk) {
      bf16x8 af[4], bfr[2];
#pragma unroll
      for (int mi = 0; mi < 4; ++mi)
        af[mi] = *(const bf16x8*)(As0 + buf * 4096 + (mi * 16 + lr) * 64 +
                                  kk * 32 + lk * 8);
#pragma unroll
      for (int ni = 0; ni < 2; ++ni)
        bfr[ni] = *(const bf16x8*)(Bs0 + buf * 16384 +
                                   (w * 32 + ni * 16 + lr) * 64 + kk * 32 +
                                   lk * 8);
#pragma unroll
      for (int mi = 0; mi < 4; ++mi)
#pragma unroll
        for (int ni = 0; ni < 2; ++ni)
          acc[mi][ni] = __builtin_amdgcn_mfma_f32_16x16x32_bf16(
              af[mi], bfr[ni], acc[mi][ni], 0, 0, 0);
    }
  };

  STAGE_T(0, 0);
  __syncthreads();
  int cur = 0;
#pragma unroll
  for (int k0 = 64; k0 < KDIM; k0 += 64) {
    STAGE_T(cur ^ 1, k0);
    compute(cur);
    __syncthreads();
    cur ^= 1;
  }
  compute(cur);

  if constexpr (EPI == 1) {
    __syncthreads();
    float* xs = (float*)smem;
#pragma unroll
    for (int mi = 0; mi < 4; ++mi) {
#pragma unroll
      for (int ni = 0; ni < 2; ++ni) {
        int c = w * 32 + ni * 16 + lr;
        float bv = bias[c];
#pragma unroll
        for (int j = 0; j < 4; ++j) {
          int rl = mi * 16 + lk * 4 + j;
          float x = acc[mi][ni][j] + bv + res[(size_t)(bm + rl) * 256 + c];
          xs[rl * 260 + c] = x;
          ((float*)o1)[(size_t)(bm + rl) * 256 + c] = x;
        }
      }
    }
    __syncthreads();
    int r = t >> 3, sub = t & 7;
    float4 xv[8];
    float sx = 0.f, sxx = 0.f;
#pragma unroll
    for (int i = 0; i < 8; ++i) {
      xv[i] = *(const float4*)&xs[r * 260 + sub * 4 + i * 32];
      sx  += xv[i].x + xv[i].y + xv[i].z + xv[i].w;
      sxx += xv[i].x * xv[i].x + xv[i].y * xv[i].y + xv[i].z * xv[i].z +
             xv[i].w * xv[i].w;
    }
#pragma unroll
    for (int d = 1; d < 8; d <<= 1) {
      sx  += __shfl_xor(sx, d, 64);
      sxx += __shfl_xor(sxx, d, 64);
    }
    float mu = sx * (1.0f / 256.0f);
    float rstd = rsqrtf(sxx * (1.0f / 256.0f) - mu * mu + 1e-5f);
#pragma unroll
    for (int i = 0; i < 8; ++i) {
      int c = sub * 4 + i * 32;
      float4 wv = *(const float4*)(w2 + c);
      float4 bv = *(const float4*)(b2 + c);
      unsigned short y0 = f2bf((xv[i].x - mu) * rstd * wv.x + bv.x);
      unsigned short y1 = f2bf((xv[i].y - mu) * rstd * wv.y + bv.y);
      unsigned short y2 = f2bf((xv[i].z - mu) * rstd * wv.z + bv.z);
      unsigned short y3 = f2bf((xv[i].w - mu) * rstd * wv.w + bv.w);
      uint2 ov;
      ov.x = ((unsigned int)y1 << 16) | y0;
      ov.y = ((unsigned int)y3 << 16) | y2;
      *(uint2*)(yln + (size_t)(bm + r) * 256 + c) = ov;
    }
  } else {
#pragma unroll
    for (int mi = 0; mi < 4; ++mi) {
#pragma unroll
      for (int ni = 0; ni < 2; ++ni) {
        int col = bn + w * 32 + ni * 16 + lr;
        float bv = bias[col];
#pragma unroll
        for (int j = 0; j < 4; ++j) {
          int rg = bm + mi * 16 + lk * 4 + j;
          float x = acc[mi][ni][j] + bv;
          if constexpr (EPI == 0) {
            if (col < 256) {
              ((unsigned short*)o1)[(size_t)rg * 256 + col] = f2h(x * kScale);
            } else {
              int c = col - 256;
              int h = c >> 6, sbit = (c >> 5) & 1, ch = c & 31;
              unsigned short* dst = sbit ? o3 : o2;
              dst[(size_t)rg * 256 + h * 32 + ch] = f2h(x);
            }
          } else if constexpr (EPI == 2) {
            float g = 0.5f * x * (1.0f + erff(x * 0.70710678118654752f));
            ((unsigned short*)o1)[(size_t)rg * 512 + col] = f2bf(g);
          } else {
            ((float*)o1)[(size_t)rg * 256 + col] =
                res[(size_t)rg * 256 + col] + x;
          }
        }
      }
    }
  }
#undef STAGE_T
}

// -------- Attention: XCD-partitioned, f16 K/V/q, v_fma_mix MACs --------------
// bid&7 -> partition (b = p>>2, hg = p&3). Wave = one (token, head-pair).
// QK: lane (m8=l>>3, ch=l&7); 8 lanes cover one member's 128B slice; per-lane
// 8 f16x f16 MACs (v_fma_mix) + shfl_xor(1,2) reduce. pos+mask bias from
// precomputed f16 posm. Softmax over members via shfl_xor(8,16,32).
// PV: lane (hp, sq, c8) -> 4 ch x 8 members; f32 weight x f16 V (v_fma_mix).
__global__ __launch_bounds__(256) void attn_kernel(
    const unsigned short* __restrict__ q, const unsigned short* __restrict__ k,
    const unsigned short* __restrict__ v, const int* __restrict__ member_idx,
    const unsigned short* __restrict__ posm,
    const unsigned short* __restrict__ bkh, const float* __restrict__ blank_v,
    unsigned short* __restrict__ outp) {
  int t = threadIdx.x;
  int w = t >> 6, l = t & 63;
  int bid = blockIdx.x;
  int part = bid & 7;
  int bb = part >> 2, hg = part & 3;
  int row = bb * kN + (bid >> 3) * 4 + w;
  const unsigned int kvbyte = (unsigned int)bb * (kN * 512u);

  __shared__ float        aw[4][2][36];    // weights + blank at [32]
  __shared__ unsigned int offs[4][32];     // member K/V row byte offsets
  __shared__ float        posl[4][2][32];  // pos+mask bias [hloc][m]

  // ---- stage ----
  {
    int m = l & 31, hloc = l >> 5;
    posl[w][hloc][m] = h2f(posm[(size_t)row * 256 + hg * 64 + l]);
    if (l < 32)
      offs[w][l] =
          kvbyte + (unsigned int)member_idx[(size_t)row * 32 + l] * 512u;
  }
  __syncthreads();

  const int m8 = l >> 3, ch = l & 7;
  const int hsel = ch >> 2;   // which head of the pair this lane's channels hit

  // per-lane q fragment: channels [ch*8, ch*8+8) of the 64-ch head-pair slice
  h8 qv8 = *(const h8*)(q + (size_t)row * 256 + hg * 64 + ch * 8);

  // ---- QK: 4 coalesced loads, 8 fma_mix each, 2-step reduce ----
  float lg[4];
#pragma unroll
  for (int i = 0; i < 4; ++i) {
    int mi = i * 8 + m8;
    const char* kp = (const char*)k + offs[w][mi] + hg * 128 + ch * 16;
    h8 kv = *(const h8*)kp;
    float p = 0.f;
#pragma unroll
    for (int e = 0; e < 8; ++e) p = fmaf((float)qv8[e], (float)kv[e], p);
    p += __shfl_xor(p, 1, 64);
    p += __shfl_xor(p, 2, 64);
    lg[i] = p + posl[w][hsel][mi];
  }

  // ---- blank logit for this lane's head (f16 blank_k) ----
  float bl = 0.f;
  {
    h8 bk8 = *(const h8*)(bkh + hg * 64 + ch * 8);
#pragma unroll
    for (int e = 0; e < 8; ++e) bl = fmaf((float)qv8[e], (float)bk8[e], bl);
    bl += __shfl_xor(bl, 1, 64);
    bl += __shfl_xor(bl, 2, 64);
    bl = fminf(fmaxf(bl, -5.0f), 5.0f);
  }

  // ---- softmax over 33 per head (ch-preserving member reduce) ----
  float mx = fmaxf(fmaxf(lg[0], lg[1]), fmaxf(lg[2], lg[3]));
  mx = fmaxf(mx, __shfl_xor(mx, 8, 64));
  mx = fmaxf(mx, __shfl_xor(mx, 16, 64));
  mx = fmaxf(mx, __shfl_xor(mx, 32, 64));
  mx = fmaxf(mx, bl);
  float e4[4], s = 0.f;
#pragma unroll
  for (int i = 0; i < 4; ++i) { e4[i] = __expf(lg[i] - mx); s += e4[i]; }
  s += __shfl_xor(s, 8, 64);
  s += __shfl_xor(s, 16, 64);
  s += __shfl_xor(s, 32, 64);
  float eb = __expf(bl - mx);
  s += eb;
  float inv = __builtin_amdgcn_rcpf(s);
  if ((ch & 3) == 0) {
#pragma unroll
    for (int i = 0; i < 4; ++i) aw[w][hsel][i * 8 + m8] = e4[i] * inv;
    if (m8 == 0) aw[w][hsel][32] = eb * inv;
  }
  __syncthreads();

  // ---- PV: lane (hp, sq, c8) -> channels c8*4..+3, members sq*8..+7 ----
  const int hp = l >> 5, sq = (l >> 3) & 3, c8 = l & 7;
  const char* vb = (const char*)v + (hg * 2 + hp) * 64 + c8 * 8;
  float a0 = 0.f, a1 = 0.f, a2 = 0.f, a3 = 0.f;
#pragma unroll
  for (int i = 0; i < 8; ++i) {
    int mm = sq * 8 + i;
    float a = aw[w][hp][mm];
    h4 u = *(const h4*)(vb + offs[w][mm]);
    a0 = fmaf(a, (float)u[0], a0);
    a1 = fmaf(a, (float)u[1], a1);
    a2 = fmaf(a, (float)u[2], a2);
    a3 = fmaf(a, (float)u[3], a3);
  }
  a0 += __shfl_xor(a0, 8, 64);  a1 += __shfl_xor(a1, 8, 64);
  a2 += __shfl_xor(a2, 8, 64);  a3 += __shfl_xor(a3, 8, 64);
  a0 += __shfl_xor(a0, 16, 64); a1 += __shfl_xor(a1, 16, 64);
  a2 += __shfl_xor(a2, 16, 64); a3 += __shfl_xor(a3, 16, 64);
  if (sq == 0) {
    float ab = aw[w][hp][32];
    int c = (hg * 2 + hp) * 32 + c8 * 4;
    float4 bv = *(const float4*)(blank_v + c);
    a0 = fmaf(ab, bv.x, a0);
    a1 = fmaf(ab, bv.y, a1);
    a2 = fmaf(ab, bv.z, a2);
    a3 = fmaf(ab, bv.w, a3);
    uint2 o;
    o.x = ((unsigned int)f2bf(a1) << 16) | f2bf(a0);
    o.y = ((unsigned int)f2bf(a3) << 16) | f2bf(a2);
    *(uint2*)(outp + (size_t)row * 256 + c) = o;
  }
}

extern "C" void kernel_launch(void* const* d_in, const int* in_sizes, int n_in,
                              void* d_out, int out_size, void* d_ws, size_t ws_size,
                              hipStream_t stream) {
  const float* feat       = (const float*)d_in[0];
  const int*   member_idx = (const int*)d_in[1];
  const float* cmask      = (const float*)d_in[2];
  const int*   pe_idx     = (const int*)d_in[3];
  const float* pre_table  = (const float*)d_in[5];
  const float* n1w        = (const float*)d_in[6];
  const float* n1b        = (const float*)d_in[7];
  const float* q_w        = (const float*)d_in[8];
  const float* q_b        = (const float*)d_in[9];
  const float* kv_w       = (const float*)d_in[10];
  const float* kv_b       = (const float*)d_in[11];
  const float* blank_k    = (const float*)d_in[12];
  const float* blank_v    = (const float*)d_in[13];
  const float* pe_w       = (const float*)d_in[14];
  const float* pe_b       = (const float*)d_in[15];
  const float* proj_w     = (const float*)d_in[16];
  const float* proj_b     = (const float*)d_in[17];
  const float* n2w        = (const float*)d_in[18];
  const float* n2b        = (const float*)d_in[19];
  const float* fc1_w      = (const float*)d_in[20];
  const float* fc1_b      = (const float*)d_in[21];
  const float* fc2_w      = (const float*)d_in[22];
  const float* fc2_b      = (const float*)d_in[23];

  float* out = (float*)d_out;
  unsigned char* ws = (unsigned char*)d_ws;

  unsigned short* xln   = (unsigned short*)(ws + 0);           // 8 MB, later attn_out
  unsigned short* q_buf = (unsigned short*)(ws + 8388608);     // 8 MB (f16), later yln
  unsigned short* k_buf = (unsigned short*)(ws + 16777216);    // 8 MB f16 \ later h1
  unsigned short* v_buf = (unsigned short*)(ws + 25165824);    // 8 MB f16 /
  unsigned short* wqkv  = (unsigned short*)(ws + 33554432);    // 384 KB
  unsigned short* wproj = (unsigned short*)(ws + 33947648);    // 128 KB
  unsigned short* wfc1  = (unsigned short*)(ws + 34078720);    // 256 KB
  unsigned short* wfc2  = (unsigned short*)(ws + 34340864);    // 256 KB
  float*          bqkv  = (float*)(ws + 34603008);             // 3 KB
  float*          pe_buf= (float*)(ws + 34606080);             // ~97 KB
  unsigned short* bkh   = (unsigned short*)(ws + 34704000);    // 512 B
  unsigned short* attn_out = xln;
  unsigned short* yln   = q_buf;
  unsigned short* h1    = k_buf;   // 16 MB spanning k_buf+v_buf
  unsigned short* posm  = (unsigned short*)out;  // d_out dead until proj: 8 MB

  cast_weights_kernel<<<2052, 256, 0, stream>>>(
      q_w, kv_w, proj_w, fc1_w, fc2_w, q_b, kv_b, blank_k, wqkv, wproj, wfc1,
      wfc2, bqkv, bkh);
  pe_kernel<<<(kTAB * 8 + 255) / 256, 256, 0, stream>>>(pre_table, pe_w, pe_b, pe_buf);
  ln_bf16_kernel<<<kRowsTotal / 4, 256, 0, stream>>>(feat, n1w, n1b, xln);
  pos_precompute_kernel<<<kRowsTotal, 256, 0, stream>>>(pe_idx, pe_buf, cmask, posm);

  gemm64<0, 256><<<dim3(kRowsTotal / 64, 3), 512, 0, stream>>>(
      xln, wqkv, bqkv, q_buf, k_buf, v_buf, nullptr, nullptr, nullptr, nullptr);

  attn_kernel<<<kRowsTotal, 256, 0, stream>>>(
      q_buf, k_buf, v_buf, member_idx, posm, bkh, blank_v, attn_out);

  gemm64<1, 256><<<dim3(kRowsTotal / 64, 1), 512, 0, stream>>>(
      attn_out, wproj, proj_b, out, nullptr, nullptr, feat, n2w, n2b, yln);

  gemm64<2, 256><<<dim3(kRowsTotal / 64, 2), 512, 0, stream>>>(
      yln, wfc1, fc1_b, h1, nullptr, nullptr, nullptr, nullptr, nullptr, nullptr);

  gemm64<3, 512><<<dim3(kRowsTotal / 64, 1), 512, 0, stream>>>(
      h1, wfc2, fc2_b, out, nullptr, nullptr, out, nullptr, nullptr, nullptr);
}

// Round 14
// 108.738 us; speedup vs baseline: 1.3459x; 1.1425x over previous
//
#include <hip/hip_runtime.h>
#include <math.h>

namespace {
constexpr int kN    = 8192;
constexpr int kC    = 256;
constexpr int kRowsTotal = 2 * kN;  // B*N = 16384
constexpr float kScale = 0.17677669529663687f;  // 32^-0.5
}

typedef __attribute__((ext_vector_type(8))) short bf16x8;
typedef __attribute__((ext_vector_type(4))) float f32x4;
typedef _Float16 h8 __attribute__((ext_vector_type(8)));
typedef _Float16 h4 __attribute__((ext_vector_type(4)));

__device__ __forceinline__ unsigned short f2bf(float f) {
  unsigned int u = __float_as_uint(f);
  u += 0x7fffu + ((u >> 16) & 1u);   // round-to-nearest-even
  return (unsigned short)(u >> 16);
}
__device__ __forceinline__ float bflo(unsigned int u) {
  return __uint_as_float(u << 16);
}
__device__ __forceinline__ float bfhi(unsigned int u) {
  return __uint_as_float(u & 0xffff0000u);
}
__device__ __forceinline__ unsigned short f2h(float f) {
  _Float16 h = (_Float16)f;
  unsigned short u;
  __builtin_memcpy(&u, &h, 2);
  return u;
}
__device__ __forceinline__ float h2f(unsigned short u) {
  _Float16 h;
  __builtin_memcpy(&h, &u, 2);
  return (float)h;
}

#define GLOAD16(g, l)                                                   \
  __builtin_amdgcn_global_load_lds(                                     \
      (const __attribute__((address_space(1))) void*)(g),               \
      (__attribute__((address_space(3))) void*)(l), 16, 0, 0)

// ---- prep: weights cast (bid<2052) | LN1 (bid<6148) | posm (else) ----------
__global__ __launch_bounds__(256) void prep_kernel(
    const float* __restrict__ qw, const float* __restrict__ kvw,
    const float* __restrict__ pjw, const float* __restrict__ f1w,
    const float* __restrict__ f2w, const float* __restrict__ qb,
    const float* __restrict__ kvb, const float* __restrict__ bk,
    const float* __restrict__ feat, const float* __restrict__ n1w,
    const float* __restrict__ n1b, const int* __restrict__ pe_idx,
    const float* __restrict__ pre_table, const float* __restrict__ pe_w,
    const float* __restrict__ pe_b, const float* __restrict__ cmask,
    unsigned short* __restrict__ wqkv, unsigned short* __restrict__ wproj,
    unsigned short* __restrict__ wfc1, unsigned short* __restrict__ wfc2,
    float* __restrict__ bqkv, unsigned short* __restrict__ bkh,
    unsigned short* __restrict__ xln, unsigned short* __restrict__ posm) {
  int bid = blockIdx.x;
  int t = threadIdx.x;
  if (bid < 2052) {
    int i = bid * 256 + t;
    if (i < 65536)       wqkv[i]            = f2bf(qw[i]);
    else if (i < 196608) wqkv[i]            = f2bf(kvw[i - 65536]);
    else if (i < 262144) wproj[i - 196608]  = f2bf(pjw[i - 196608]);
    else if (i < 393216) wfc1[i - 262144]   = f2bf(f1w[i - 262144]);
    else if (i < 524288) wfc2[i - 393216]   = f2bf(f2w[i - 393216]);
    else if (i < 524544) bqkv[i - 524288]   = qb[i - 524288];
    else if (i < 525056) bqkv[i - 524288]   = kvb[i - 524544];
    else if (i < 525312) bkh[i - 525056]    = f2h(bk[i - 525056]);
  } else if (bid < 6148) {
    int row = (bid - 2052) * 4 + (t >> 6);
    int l = t & 63;
    float4 v = *(const float4*)(feat + (size_t)row * kC + l * 4);
    float s  = v.x + v.y + v.z + v.w;
    float s2 = v.x * v.x + v.y * v.y + v.z * v.z + v.w * v.w;
#pragma unroll
    for (int d = 1; d < 64; d <<= 1) {
      s  += __shfl_xor(s, d, 64);
      s2 += __shfl_xor(s2, d, 64);
    }
    float mu = s * (1.0f / kC);
    float rstd = rsqrtf(s2 * (1.0f / kC) - mu * mu + 1e-5f);
    float4 wv = *(const float4*)(n1w + l * 4);
    float4 bv = *(const float4*)(n1b + l * 4);
    uint2 ov;
    ov.x = ((unsigned int)f2bf((v.y - mu) * rstd * wv.y + bv.y) << 16) |
           f2bf((v.x - mu) * rstd * wv.x + bv.x);
    ov.y = ((unsigned int)f2bf((v.w - mu) * rstd * wv.w + bv.w) << 16) |
           f2bf((v.z - mu) * rstd * wv.z + bv.z);
    *(uint2*)(xln + (size_t)row * kC + l * 4) = ov;
  } else {
    int i = (bid - 6148) * 256 + t;
    int row = i >> 8, m = (i >> 3) & 31, h = i & 7;
    int idx = pe_idx[(size_t)row * 32 + m];
    float acc = pe_b[h];
#pragma unroll
    for (int f = 0; f < 5; ++f)
      acc += pre_table[idx * 5 + f] * pe_w[h * 5 + f];
    acc += (1.0f - cmask[(size_t)row * 32 + m]) * -100.0f;
    posm[(size_t)row * 256 + h * 32 + m] = f2h(acc);
  }
}

// ---- bf16 MFMA GEMM (QKV only): BM=64, BN=256, 8 waves, BK=64 dbuf ---------
template <int EPI, int KDIM>
__global__ __launch_bounds__(512) void gemm64(
    const unsigned short* __restrict__ A, const unsigned short* __restrict__ Wt,
    const float* __restrict__ bias, void* __restrict__ o1,
    unsigned short* __restrict__ o2, unsigned short* __restrict__ o3) {
  __shared__ alignas(16) unsigned short smem[40960];
  unsigned short* As0 = smem;
  unsigned short* Bs0 = smem + 8192;
  int t = threadIdx.x;
  int w = t >> 6, l = t & 63;
  int bm = blockIdx.x * 64, bn = blockIdx.y * 256;

  f32x4 acc[4][2] = {};

  const size_t aoff = (size_t)(bm + w * 8 + (l >> 3)) * KDIM + (l & 7) * 8;
  const size_t boff = (size_t)(bn + w * 32 + (l >> 3)) * KDIM + (l & 7) * 8;
  const int lr = l & 15, lk = l >> 4;

#define STAGE_T(buf, k0)                                                      \
  do {                                                                        \
    GLOAD16(A + aoff + (k0), As0 + (buf)*4096 + w * 512 + l * 8);             \
    GLOAD16(Wt + boff + (k0), Bs0 + (buf)*16384 + w * 2048 + l * 8);          \
    GLOAD16(Wt + boff + (k0) + (size_t)8 * KDIM,                              \
            Bs0 + (buf)*16384 + w * 2048 + 512 + l * 8);                      \
    GLOAD16(Wt + boff + (k0) + (size_t)16 * KDIM,                             \
            Bs0 + (buf)*16384 + w * 2048 + 1024 + l * 8);                     \
    GLOAD16(Wt + boff + (k0) + (size_t)24 * KDIM,                             \
            Bs0 + (buf)*16384 + w * 2048 + 1536 + l * 8);                     \
  } while (0)

  auto compute = [&](int buf) {
#pragma unroll
    for (int kk = 0; kk < 2; ++kk) {
      bf16x8 af[4], bfr[2];
#pragma unroll
      for (int mi = 0; mi < 4; ++mi)
        af[mi] = *(const bf16x8*)(As0 + buf * 4096 + (mi * 16 + lr) * 64 +
                                  kk * 32 + lk * 8);
#pragma unroll
      for (int ni = 0; ni < 2; ++ni)
        bfr[ni] = *(const bf16x8*)(Bs0 + buf * 16384 +
                                   (w * 32 + ni * 16 + lr) * 64 + kk * 32 +
                                   lk * 8);
#pragma unroll
      for (int mi = 0; mi < 4; ++mi)
#pragma unroll
        for (int ni = 0; ni < 2; ++ni)
          acc[mi][ni] = __builtin_amdgcn_mfma_f32_16x16x32_bf16(
              af[mi], bfr[ni], acc[mi][ni], 0, 0, 0);
    }
  };

  STAGE_T(0, 0);
  __syncthreads();
  int cur = 0;
#pragma unroll
  for (int k0 = 64; k0 < KDIM; k0 += 64) {
    STAGE_T(cur ^ 1, k0);
    compute(cur);
    __syncthreads();
    cur ^= 1;
  }
  compute(cur);

#pragma unroll
  for (int mi = 0; mi < 4; ++mi) {
#pragma unroll
    for (int ni = 0; ni < 2; ++ni) {
      int col = bn + w * 32 + ni * 16 + lr;
      float bv = bias[col];
#pragma unroll
      for (int j = 0; j < 4; ++j) {
        int rg = bm + mi * 16 + lk * 4 + j;
        float x = acc[mi][ni][j] + bv;
        if (col < 256) {
          ((unsigned short*)o1)[(size_t)rg * 256 + col] = f2h(x * kScale);
        } else {
          int c = col - 256;
          int h = c >> 6, sbit = (c >> 5) & 1, ch = c & 31;
          unsigned short* dst = sbit ? o3 : o2;
          dst[(size_t)rg * 256 + h * 32 + ch] = f2h(x);
        }
      }
    }
  }
#undef STAGE_T
}

// ---- fused proj+residual+LN2+fc1+gelu+fc2+residual, 64 rows per block ------
// LDS (shorts; 66560 total = 133120 B):
//  proj:  As dbuf [0,8192), Bs dbuf [8192,40960)
//  xs f32 [0,33280)shorts-as-floats (=66560B)        (after proj)
//  fc1 Bs dbuf (BK=32): [33280,49664)                 (coexists with xs/yln)
//  yln bf16 [64][264]: [49664,66560)                  (alive through fc1)
//  h1  bf16 [64][520]: [0,33280)                      (over dead xs)
//  fc2 Bs dbuf (BK=64): [33280,66048)                 (over dead fc1Bs+yln)
__global__ __launch_bounds__(512) void mlp_fused(
    const unsigned short* __restrict__ A,    // attn_out bf16 [16384][256]
    const unsigned short* __restrict__ Wp,   // wproj bf16 [256][256]
    const float* __restrict__ pbias,         // proj_b
    const float* __restrict__ feat,          // residual f32
    const float* __restrict__ w2, const float* __restrict__ b2,
    const unsigned short* __restrict__ W1, const float* __restrict__ b1,
    const unsigned short* __restrict__ W2, const float* __restrict__ b2f,
    float* __restrict__ outp) {
  __shared__ alignas(16) unsigned short sm[66560];
  int t = threadIdx.x;
  int w = t >> 6, l = t & 63;
  int bm = blockIdx.x * 64;
  const int lr = l & 15, lk = l >> 4;

  // ---------------- proj ----------------
  f32x4 accp[4][2] = {};
  {
    const size_t aoff = (size_t)(bm + w * 8 + (l >> 3)) * 256 + (l & 7) * 8;
    const size_t boff = (size_t)(w * 32 + (l >> 3)) * 256 + (l & 7) * 8;
#define PSTAGE(buf, k0)                                                       \
  do {                                                                        \
    GLOAD16(A + aoff + (k0), sm + (buf)*4096 + w * 512 + l * 8);              \
    GLOAD16(Wp + boff + (k0), sm + 8192 + (buf)*16384 + w * 2048 + l * 8);    \
    GLOAD16(Wp + boff + (k0) + (size_t)2048,                                  \
            sm + 8192 + (buf)*16384 + w * 2048 + 512 + l * 8);                \
    GLOAD16(Wp + boff + (k0) + (size_t)4096,                                  \
            sm + 8192 + (buf)*16384 + w * 2048 + 1024 + l * 8);               \
    GLOAD16(Wp + boff + (k0) + (size_t)6144,                                  \
            sm + 8192 + (buf)*16384 + w * 2048 + 1536 + l * 8);               \
  } while (0)
    auto computeP = [&](int buf) {
#pragma unroll
      for (int kk = 0; kk < 2; ++kk) {
        bf16x8 af[4], bfr[2];
#pragma unroll
        for (int mi = 0; mi < 4; ++mi)
          af[mi] = *(const bf16x8*)(sm + buf * 4096 + (mi * 16 + lr) * 64 +
                                    kk * 32 + lk * 8);
#pragma unroll
        for (int ni = 0; ni < 2; ++ni)
          bfr[ni] = *(const bf16x8*)(sm + 8192 + buf * 16384 +
                                     (w * 32 + ni * 16 + lr) * 64 + kk * 32 +
                                     lk * 8);
#pragma unroll
        for (int mi = 0; mi < 4; ++mi)
#pragma unroll
          for (int ni = 0; ni < 2; ++ni)
            accp[mi][ni] = __builtin_amdgcn_mfma_f32_16x16x32_bf16(
                af[mi], bfr[ni], accp[mi][ni], 0, 0, 0);
      }
    };
    PSTAGE(0, 0);
    __syncthreads();
    int cur = 0;
#pragma unroll
    for (int k0 = 64; k0 < 256; k0 += 64) {
      PSTAGE(cur ^ 1, k0);
      computeP(cur);
      __syncthreads();
      cur ^= 1;
    }
    computeP(cur);
#undef PSTAGE
  }

  // ---------------- x = proj + bias + feat (regs + LDS) ----------------
  f32x4 xr[4][2];
  float* xs = (float*)sm;
  __syncthreads();
#pragma unroll
  for (int mi = 0; mi < 4; ++mi) {
#pragma unroll
    for (int ni = 0; ni < 2; ++ni) {
      int c = w * 32 + ni * 16 + lr;
      float bv = pbias[c];
#pragma unroll
      for (int j = 0; j < 4; ++j) {
        int rl = mi * 16 + lk * 4 + j;
        float x = accp[mi][ni][j] + bv + feat[(size_t)(bm + rl) * 256 + c];
        xr[mi][ni][j] = x;
        xs[rl * 260 + c] = x;
      }
    }
  }
  __syncthreads();

  // ---------------- LN2 -> yln (LDS bf16 [64][264] @49664) ----------------
  {
    int r = t >> 3, sub = t & 7;
    float4 xv[8];
    float sx = 0.f, sxx = 0.f;
#pragma unroll
    for (int i = 0; i < 8; ++i) {
      xv[i] = *(const float4*)&xs[r * 260 + sub * 4 + i * 32];
      sx  += xv[i].x + xv[i].y + xv[i].z + xv[i].w;
      sxx += xv[i].x * xv[i].x + xv[i].y * xv[i].y + xv[i].z * xv[i].z +
             xv[i].w * xv[i].w;
    }
#pragma unroll
    for (int d = 1; d < 8; d <<= 1) {
      sx  += __shfl_xor(sx, d, 64);
      sxx += __shfl_xor(sxx, d, 64);
    }
    float mu = sx * (1.0f / 256.0f);
    float rstd = rsqrtf(sxx * (1.0f / 256.0f) - mu * mu + 1e-5f);
#pragma unroll
    for (int i = 0; i < 8; ++i) {
      int c = sub * 4 + i * 32;
      float4 wv = *(const float4*)(w2 + c);
      float4 bv = *(const float4*)(b2 + c);
      uint2 ov;
      ov.x = ((unsigned int)f2bf((xv[i].y - mu) * rstd * wv.y + bv.y) << 16) |
             f2bf((xv[i].x - mu) * rstd * wv.x + bv.x);
      ov.y = ((unsigned int)f2bf((xv[i].w - mu) * rstd * wv.w + bv.w) << 16) |
             f2bf((xv[i].z - mu) * rstd * wv.z + bv.z);
      *(uint2*)&sm[49664 + r * 264 + c] = ov;
    }
  }
  __syncthreads();

  // ---------------- fc1 + gelu -> h1 (LDS bf16 [64][520] @0) ----------------
  const int FB = 33280;
#define F1STAGE(buf, k0, c)                                                   \
  do {                                                                        \
    GLOAD16(W1 + (size_t)((c)*256 + w * 32 + (l >> 2)) * 256 + (k0) +         \
                (l & 3) * 8,                                                  \
            sm + FB + (buf)*8192 + w * 1024 + l * 8);                         \
    GLOAD16(W1 + (size_t)((c)*256 + w * 32 + 16 + (l >> 2)) * 256 + (k0) +    \
                (l & 3) * 8,                                                  \
            sm + FB + (buf)*8192 + w * 1024 + 512 + l * 8);                   \
  } while (0)
#pragma unroll
  for (int c = 0; c < 2; ++c) {
    f32x4 accf[4][2] = {};
    auto computeF1 = [&](int buf, int ka) {
      bf16x8 af[4], bfr[2];
#pragma unroll
      for (int mi = 0; mi < 4; ++mi)
        af[mi] =
            *(const bf16x8*)(sm + 49664 + (mi * 16 + lr) * 264 + ka + lk * 8);
#pragma unroll
      for (int ni = 0; ni < 2; ++ni)
        bfr[ni] = *(const bf16x8*)(sm + FB + buf * 8192 +
                                   (w * 32 + ni * 16 + lr) * 32 + lk * 8);
#pragma unroll
      for (int mi = 0; mi < 4; ++mi)
#pragma unroll
        for (int ni = 0; ni < 2; ++ni)
          accf[mi][ni] = __builtin_amdgcn_mfma_f32_16x16x32_bf16(
              af[mi], bfr[ni], accf[mi][ni], 0, 0, 0);
    };
    F1STAGE(0, 0, c);
    __syncthreads();
    int cur = 0;
#pragma unroll
    for (int k0 = 32; k0 < 256; k0 += 32) {
      F1STAGE(cur ^ 1, k0, c);
      computeF1(cur, k0 - 32);
      __syncthreads();
      cur ^= 1;
    }
    computeF1(cur, 224);
    __syncthreads();
    // gelu -> h1 chunk
#pragma unroll
    for (int mi = 0; mi < 4; ++mi) {
#pragma unroll
      for (int ni = 0; ni < 2; ++ni) {
        int colg = c * 256 + w * 32 + ni * 16 + lr;
        float bv = b1[colg];
#pragma unroll
        for (int j = 0; j < 4; ++j) {
          float x = accf[mi][ni][j] + bv;
          float g = 0.5f * x * (1.0f + erff(x * 0.70710678118654752f));
          sm[(mi * 16 + lk * 4 + j) * 520 + colg] = f2bf(g);
        }
      }
    }
  }
#undef F1STAGE
  __syncthreads();

  // ---------------- fc2 (K=512, BK=64) + residual -> out ----------------
  f32x4 acc2[4][2] = {};
#define F2STAGE(buf, k0)                                                      \
  do {                                                                        \
    GLOAD16(W2 + (size_t)(w * 32 + (l >> 3)) * 512 + (k0) + (l & 7) * 8,      \
            sm + FB + (buf)*16384 + w * 2048 + l * 8);                        \
    GLOAD16(W2 + (size_t)(w * 32 + 8 + (l >> 3)) * 512 + (k0) + (l & 7) * 8,  \
            sm + FB + (buf)*16384 + w * 2048 + 512 + l * 8);                  \
    GLOAD16(W2 + (size_t)(w * 32 + 16 + (l >> 3)) * 512 + (k0) + (l & 7) * 8, \
            sm + FB + (buf)*16384 + w * 2048 + 1024 + l * 8);                 \
    GLOAD16(W2 + (size_t)(w * 32 + 24 + (l >> 3)) * 512 + (k0) + (l & 7) * 8, \
            sm + FB + (buf)*16384 + w * 2048 + 1536 + l * 8);                 \
  } while (0)
  {
    auto computeF2 = [&](int buf, int ka) {
#pragma unroll
      for (int kk = 0; kk < 2; ++kk) {
        bf16x8 af[4], bfr[2];
#pragma unroll
        for (int mi = 0; mi < 4; ++mi)
          af[mi] = *(const bf16x8*)(sm + (mi * 16 + lr) * 520 + ka + kk * 32 +
                                    lk * 8);
#pragma unroll
        for (int ni = 0; ni < 2; ++ni)
          bfr[ni] = *(const bf16x8*)(sm + FB + buf * 16384 +
                                     (w * 32 + ni * 16 + lr) * 64 + kk * 32 +
                                     lk * 8);
#pragma unroll
        for (int mi = 0; mi < 4; ++mi)
#pragma unroll
          for (int ni = 0; ni < 2; ++ni)
            acc2[mi][ni] = __builtin_amdgcn_mfma_f32_16x16x32_bf16(
                af[mi], bfr[ni], acc2[mi][ni], 0, 0, 0);
      }
    };
    F2STAGE(0, 0);
    __syncthreads();
    int cur = 0;
#pragma unroll
    for (int k0 = 64; k0 < 512; k0 += 64) {
      F2STAGE(cur ^ 1, k0);
      computeF2(cur, k0 - 64);
      __syncthreads();
      cur ^= 1;
    }
    computeF2(cur, 448);
  }
#undef F2STAGE

#pragma unroll
  for (int mi = 0; mi < 4; ++mi) {
#pragma unroll
    for (int ni = 0; ni < 2; ++ni) {
      int col = w * 32 + ni * 16 + lr;
      float bv = b2f[col];
#pragma unroll
      for (int j = 0; j < 4; ++j) {
        int rg = bm + mi * 16 + lk * 4 + j;
        outp[(size_t)rg * 256 + col] = xr[mi][ni][j] + acc2[mi][ni][j] + bv;
      }
    }
  }
}

// -------- Attention (r13, unchanged): XCD-partitioned, f16, fma_mix ---------
__global__ __launch_bounds__(256) void attn_kernel(
    const unsigned short* __restrict__ q, const unsigned short* __restrict__ k,
    const unsigned short* __restrict__ v, const int* __restrict__ member_idx,
    const unsigned short* __restrict__ posm,
    const unsigned short* __restrict__ bkh, const float* __restrict__ blank_v,
    unsigned short* __restrict__ outp) {
  int t = threadIdx.x;
  int w = t >> 6, l = t & 63;
  int bid = blockIdx.x;
  int part = bid & 7;
  int bb = part >> 2, hg = part & 3;
  int row = bb * kN + (bid >> 3) * 4 + w;
  const unsigned int kvbyte = (unsigned int)bb * (kN * 512u);

  __shared__ float        aw[4][2][36];
  __shared__ unsigned int offs[4][32];
  __shared__ float        posl[4][2][32];

  {
    int m = l & 31, hloc = l >> 5;
    posl[w][hloc][m] = h2f(posm[(size_t)row * 256 + hg * 64 + l]);
    if (l < 32)
      offs[w][l] =
          kvbyte + (unsigned int)member_idx[(size_t)row * 32 + l] * 512u;
  }
  __syncthreads();

  const int m8 = l >> 3, ch = l & 7;
  const int hsel = ch >> 2;

  h8 qv8 = *(const h8*)(q + (size_t)row * 256 + hg * 64 + ch * 8);

  float lg[4];
#pragma unroll
  for (int i = 0; i < 4; ++i) {
    int mi = i * 8 + m8;
    const char* kp = (const char*)k + offs[w][mi] + hg * 128 + ch * 16;
    h8 kv = *(const h8*)kp;
    float p = 0.f;
#pragma unroll
    for (int e = 0; e < 8; ++e) p = fmaf((float)qv8[e], (float)kv[e], p);
    p += __shfl_xor(p, 1, 64);
    p += __shfl_xor(p, 2, 64);
    lg[i] = p + posl[w][hsel][mi];
  }

  float bl = 0.f;
  {
    h8 bk8 = *(const h8*)(bkh + hg * 64 + ch * 8);
#pragma unroll
    for (int e = 0; e < 8; ++e) bl = fmaf((float)qv8[e], (float)bk8[e], bl);
    bl += __shfl_xor(bl, 1, 64);
    bl += __shfl_xor(bl, 2, 64);
    bl = fminf(fmaxf(bl, -5.0f), 5.0f);
  }

  float mx = fmaxf(fmaxf(lg[0], lg[1]), fmaxf(lg[2], lg[3]));
  mx = fmaxf(mx, __shfl_xor(mx, 8, 64));
  mx = fmaxf(mx, __shfl_xor(mx, 16, 64));
  mx = fmaxf(mx, __shfl_xor(mx, 32, 64));
  mx = fmaxf(mx, bl);
  float e4[4], s = 0.f;
#pragma unroll
  for (int i = 0; i < 4; ++i) { e4[i] = __expf(lg[i] - mx); s += e4[i]; }
  s += __shfl_xor(s, 8, 64);
  s += __shfl_xor(s, 16, 64);
  s += __shfl_xor(s, 32, 64);
  float eb = __expf(bl - mx);
  s += eb;
  float inv = __builtin_amdgcn_rcpf(s);
  if ((ch & 3) == 0) {
#pragma unroll
    for (int i = 0; i < 4; ++i) aw[w][hsel][i * 8 + m8] = e4[i] * inv;
    if (m8 == 0) aw[w][hsel][32] = eb * inv;
  }
  __syncthreads();

  const int hp = l >> 5, sq = (l >> 3) & 3, c8 = l & 7;
  const char* vb = (const char*)v + (hg * 2 + hp) * 64 + c8 * 8;
  float a0 = 0.f, a1 = 0.f, a2 = 0.f, a3 = 0.f;
#pragma unroll
  for (int i = 0; i < 8; ++i) {
    int mm = sq * 8 + i;
    float a = aw[w][hp][mm];
    h4 u = *(const h4*)(vb + offs[w][mm]);
    a0 = fmaf(a, (float)u[0], a0);
    a1 = fmaf(a, (float)u[1], a1);
    a2 = fmaf(a, (float)u[2], a2);
    a3 = fmaf(a, (float)u[3], a3);
  }
  a0 += __shfl_xor(a0, 8, 64);  a1 += __shfl_xor(a1, 8, 64);
  a2 += __shfl_xor(a2, 8, 64);  a3 += __shfl_xor(a3, 8, 64);
  a0 += __shfl_xor(a0, 16, 64); a1 += __shfl_xor(a1, 16, 64);
  a2 += __shfl_xor(a2, 16, 64); a3 += __shfl_xor(a3, 16, 64);
  if (sq == 0) {
    float ab = aw[w][hp][32];
    int c = (hg * 2 + hp) * 32 + c8 * 4;
    float4 bv = *(const float4*)(blank_v + c);
    a0 = fmaf(ab, bv.x, a0);
    a1 = fmaf(ab, bv.y, a1);
    a2 = fmaf(ab, bv.z, a2);
    a3 = fmaf(ab, bv.w, a3);
    uint2 o;
    o.x = ((unsigned int)f2bf(a1) << 16) | f2bf(a0);
    o.y = ((unsigned int)f2bf(a3) << 16) | f2bf(a2);
    *(uint2*)(outp + (size_t)row * 256 + c) = o;
  }
}

extern "C" void kernel_launch(void* const* d_in, const int* in_sizes, int n_in,
                              void* d_out, int out_size, void* d_ws, size_t ws_size,
                              hipStream_t stream) {
  const float* feat       = (const float*)d_in[0];
  const int*   member_idx = (const int*)d_in[1];
  const float* cmask      = (const float*)d_in[2];
  const int*   pe_idx     = (const int*)d_in[3];
  const float* pre_table  = (const float*)d_in[5];
  const float* n1w        = (const float*)d_in[6];
  const float* n1b        = (const float*)d_in[7];
  const float* q_w        = (const float*)d_in[8];
  const float* q_b        = (const float*)d_in[9];
  const float* kv_w       = (const float*)d_in[10];
  const float* kv_b       = (const float*)d_in[11];
  const float* blank_k    = (const float*)d_in[12];
  const float* blank_v    = (const float*)d_in[13];
  const float* pe_w       = (const float*)d_in[14];
  const float* pe_b       = (const float*)d_in[15];
  const float* proj_w     = (const float*)d_in[16];
  const float* proj_b     = (const float*)d_in[17];
  const float* n2w        = (const float*)d_in[18];
  const float* n2b        = (const float*)d_in[19];
  const float* fc1_w      = (const float*)d_in[20];
  const float* fc1_b      = (const float*)d_in[21];
  const float* fc2_w      = (const float*)d_in[22];
  const float* fc2_b      = (const float*)d_in[23];

  float* out = (float*)d_out;
  unsigned char* ws = (unsigned char*)d_ws;

  unsigned short* xln   = (unsigned short*)(ws + 0);           // 8 MB, later attn_out
  unsigned short* q_buf = (unsigned short*)(ws + 8388608);     // 8 MB f16
  unsigned short* k_buf = (unsigned short*)(ws + 16777216);    // 8 MB f16
  unsigned short* v_buf = (unsigned short*)(ws + 25165824);    // 8 MB f16
  unsigned short* wqkv  = (unsigned short*)(ws + 33554432);    // 384 KB
  unsigned short* wproj = (unsigned short*)(ws + 33947648);    // 128 KB
  unsigned short* wfc1  = (unsigned short*)(ws + 34078720);    // 256 KB
  unsigned short* wfc2  = (unsigned short*)(ws + 34340864);    // 256 KB
  float*          bqkv  = (float*)(ws + 34603008);             // 3 KB
  unsigned short* bkh   = (unsigned short*)(ws + 34606080);    // 512 B
  unsigned short* attn_out = xln;
  unsigned short* posm  = (unsigned short*)out;  // d_out dead until mlp_fused

  prep_kernel<<<22532, 256, 0, stream>>>(
      q_w, kv_w, proj_w, fc1_w, fc2_w, q_b, kv_b, blank_k, feat, n1w, n1b,
      pe_idx, pre_table, pe_w, pe_b, cmask, wqkv, wproj, wfc1, wfc2, bqkv,
      bkh, xln, posm);

  gemm64<0, 256><<<dim3(kRowsTotal / 64, 3), 512, 0, stream>>>(
      xln, wqkv, bqkv, q_buf, k_buf, v_buf);

  attn_kernel<<<kRowsTotal, 256, 0, stream>>>(
      q_buf, k_buf, v_buf, member_idx, posm, bkh, blank_v, attn_out);

  mlp_fused<<<kRowsTotal / 64, 512, 0, stream>>>(
      attn_out, wproj, proj_b, feat, n2w, n2b, wfc1, fc1_b, wfc2, fc2_b, out);
}